// Round 1
// baseline (1167.681 us; speedup 1.0000x reference)
//
#include <hip/hip_runtime.h>
#include <hip/hip_bf16.h>
#include <math.h>

#define NA 65536
#define MAXSEG 160

// degree segment starts: 0, 4096, 16384, 36864, 57344
// sizes: 4096, 12288, 20480, 20480, 8192  (all divisible by 16)

__device__ __forceinline__ int seg_of_block(int bt, int& tile) {
    // tiles of 16 atoms: 256, 768, 1280, 1280, 512 per segment (cum 256,1024,2304,3584,4096)
    if (bt < 256)  { tile = bt;        return 0; }
    if (bt < 1024) { tile = bt - 256;  return 1; }
    if (bt < 2304) { tile = bt - 1024; return 2; }
    if (bt < 3584) { tile = bt - 2304; return 3; }
    tile = bt - 3584; return 4;
}

__global__ void zero_count_kernel(int* __restrict__ count) {
    int i = blockIdx.x * 256 + threadIdx.x;
    if (i < 1024) count[i] = 0;
}

__global__ void bucket_kernel(const int* __restrict__ mem, int* __restrict__ count,
                              int* __restrict__ list) {
    int i = blockIdx.x * 256 + threadIdx.x;   // grid 256x256 = 65536
    int seg = mem[i];
    int pos = atomicAdd(&count[seg], 1);
    if (pos < MAXSEG) list[seg * MAXSEG + pos] = i;
}

// Graph conv + bias + relu + BN. One kernel covers all 5 degree segments.
// gcW: (9, K, 256), gcb: (9, 256), bnp: (4, 256) = [g, b, m, v]
template<int K>
__global__ __launch_bounds__(256) void conv_kernel(
    const float* __restrict__ x,      // (NA, K)
    const int* __restrict__ a1, const int* __restrict__ a2,
    const int* __restrict__ a3, const int* __restrict__ a4,
    const float* __restrict__ gcW, const float* __restrict__ gcb,
    const float* __restrict__ bnp,
    float* __restrict__ out)          // (NA, 256)
{
    constexpr int KP = (K + 3) & ~3;   // 76 or 256 (keeps float4 alignment)
    constexpr int TILE = 16;
    __shared__ float xs[TILE * KP];
    __shared__ float xr[TILE * KP];

    int tile; int d = seg_of_block(blockIdx.x, tile);
    int start = (d == 0) ? 0 : (d == 1) ? 4096 : (d == 2) ? 16384 : (d == 3) ? 36864 : 57344;
    const int* adj = (d == 1) ? a1 : (d == 2) ? a2 : (d == 3) ? a3 : (d == 4) ? a4 : nullptr;
    int row0 = tile * TILE;

    // stage self rows
    for (int idx = threadIdx.x; idx < TILE * K; idx += 256) {
        int r = idx / K, col = idx - r * K;
        xs[r * KP + col] = x[(size_t)(start + row0 + r) * K + col];
    }
    // stage neighbor-sum rows
    if (d > 0) {
        for (int idx = threadIdx.x; idx < TILE * K; idx += 256) {
            int r = idx / K, col = idx - r * K;
            const int* arow = adj + (size_t)(row0 + r) * d;
            float s = 0.f;
            for (int j = 0; j < d; j++) s += x[(size_t)arow[j] * K + col];
            xr[r * KP + col] = s;
        }
    }
    __syncthreads();

    int c = threadIdx.x;              // output channel 0..255
    const float* Ws; const float* Wn = nullptr; float bias;
    if (d == 0) {
        Ws = gcW + (size_t)8 * K * 256;
        bias = gcb[8 * 256 + c];
    } else {
        Wn = gcW + (size_t)(2 * (d - 1)) * K * 256;
        Ws = gcW + (size_t)(2 * d - 1) * K * 256;
        bias = gcb[(2 * (d - 1)) * 256 + c] + gcb[(2 * d - 1) * 256 + c];
    }

    float acc[TILE];
#pragma unroll
    for (int a = 0; a < TILE; a++) acc[a] = 0.f;

    constexpr int K4 = K / 4;
    if (d > 0) {
        for (int k4 = 0; k4 < K4; k4++) {
            int k = 4 * k4;
            float s0 = Ws[(k + 0) * 256 + c], s1 = Ws[(k + 1) * 256 + c];
            float s2 = Ws[(k + 2) * 256 + c], s3 = Ws[(k + 3) * 256 + c];
            float n0 = Wn[(k + 0) * 256 + c], n1 = Wn[(k + 1) * 256 + c];
            float n2 = Wn[(k + 2) * 256 + c], n3 = Wn[(k + 3) * 256 + c];
#pragma unroll
            for (int a = 0; a < TILE; a++) {
                float4 xv = *(const float4*)(xs + a * KP + k);
                float4 rv = *(const float4*)(xr + a * KP + k);
                acc[a] = fmaf(xv.x, s0, acc[a]); acc[a] = fmaf(rv.x, n0, acc[a]);
                acc[a] = fmaf(xv.y, s1, acc[a]); acc[a] = fmaf(rv.y, n1, acc[a]);
                acc[a] = fmaf(xv.z, s2, acc[a]); acc[a] = fmaf(rv.z, n2, acc[a]);
                acc[a] = fmaf(xv.w, s3, acc[a]); acc[a] = fmaf(rv.w, n3, acc[a]);
            }
        }
        for (int k = K4 * 4; k < K; k++) {
            float sw = Ws[k * 256 + c], nw = Wn[k * 256 + c];
#pragma unroll
            for (int a = 0; a < TILE; a++)
                acc[a] += xs[a * KP + k] * sw + xr[a * KP + k] * nw;
        }
    } else {
        for (int k4 = 0; k4 < K4; k4++) {
            int k = 4 * k4;
            float s0 = Ws[(k + 0) * 256 + c], s1 = Ws[(k + 1) * 256 + c];
            float s2 = Ws[(k + 2) * 256 + c], s3 = Ws[(k + 3) * 256 + c];
#pragma unroll
            for (int a = 0; a < TILE; a++) {
                float4 xv = *(const float4*)(xs + a * KP + k);
                acc[a] = fmaf(xv.x, s0, acc[a]); acc[a] = fmaf(xv.y, s1, acc[a]);
                acc[a] = fmaf(xv.z, s2, acc[a]); acc[a] = fmaf(xv.w, s3, acc[a]);
            }
        }
        for (int k = K4 * 4; k < K; k++) {
            float sw = Ws[k * 256 + c];
#pragma unroll
            for (int a = 0; a < TILE; a++)
                acc[a] += xs[a * KP + k] * sw;
        }
    }

    // bias + relu + BN
    float g = bnp[c], bb = bnp[256 + c], m = bnp[512 + c], v = bnp[768 + c];
    float scale = g * rsqrtf(v + 1e-3f);
#pragma unroll
    for (int a = 0; a < TILE; a++) {
        float val = fmaxf(acc[a] + bias, 0.f);
        val = fmaf(scale, val - m, bb);
        out[(size_t)(start + row0 + a) * 256 + c] = val;
    }
}

// Graph pool: per atom elementwise max over {self, neighbors}. One wave per atom.
__global__ __launch_bounds__(256) void pool_kernel(
    const float* __restrict__ x,      // (NA, 256)
    const int* __restrict__ a1, const int* __restrict__ a2,
    const int* __restrict__ a3, const int* __restrict__ a4,
    float* __restrict__ out)          // (NA, 256)
{
    int atom = blockIdx.x * 4 + (threadIdx.x >> 6);
    int lane = threadIdx.x & 63;
    float4 m = ((const float4*)(x + (size_t)atom * 256))[lane];
    int d, loc; const int* adj = nullptr;
    if (atom < 4096)       { d = 0; loc = 0; }
    else if (atom < 16384) { d = 1; adj = a1; loc = atom - 4096; }
    else if (atom < 36864) { d = 2; adj = a2; loc = atom - 16384; }
    else if (atom < 57344) { d = 3; adj = a3; loc = atom - 36864; }
    else                   { d = 4; adj = a4; loc = atom - 57344; }
    for (int j = 0; j < d; j++) {
        int nb = adj[(size_t)loc * d + j];
        float4 nv = ((const float4*)(x + (size_t)nb * 256))[lane];
        m.x = fmaxf(m.x, nv.x); m.y = fmaxf(m.y, nv.y);
        m.z = fmaxf(m.z, nv.z); m.w = fmaxf(m.w, nv.w);
    }
    ((float4*)(out + (size_t)atom * 256))[lane] = m;
}

// Fused dense(256->512)+relu+BN3 + segment sum/max + tanh -> fp (1024,1024).
// One block (512 threads = channel) per segment; atoms from bucket list.
__global__ __launch_bounds__(512) void dense_seg_kernel(
    const float* __restrict__ x,      // (NA, 256) pooled2
    const float* __restrict__ W,      // (256, 512)
    const float* __restrict__ bias,   // (512,)
    const float* __restrict__ bnp,    // (4, 512)
    const int* __restrict__ count, const int* __restrict__ list,
    float* __restrict__ fp)           // (1024, 1024)
{
    constexpr int TILE = 32;
    __shared__ float xs[TILE * 256];
    int seg = blockIdx.x;
    int c = threadIdx.x;              // 0..511
    int n = count[seg]; if (n > MAXSEG) n = MAXSEG;
    float b = bias[c];
    float g = bnp[c], bb = bnp[512 + c], m = bnp[1024 + c], v = bnp[1536 + c];
    float scale = g * rsqrtf(v + 1e-3f);
    float sum = 0.f, mx = -INFINITY;

    for (int base = 0; base < n; base += TILE) {
        int nt = min(TILE, n - base);
        __syncthreads();
        for (int idx = threadIdx.x; idx < nt * 256; idx += 512) {
            int r = idx >> 8, col = idx & 255;
            xs[r * 256 + col] = x[(size_t)list[seg * MAXSEG + base + r] * 256 + col];
        }
        __syncthreads();
        float acc[TILE];
#pragma unroll
        for (int a = 0; a < TILE; a++) acc[a] = 0.f;
        for (int k4 = 0; k4 < 64; k4++) {
            int k = 4 * k4;
            float w0 = W[(k + 0) * 512 + c], w1 = W[(k + 1) * 512 + c];
            float w2 = W[(k + 2) * 512 + c], w3 = W[(k + 3) * 512 + c];
#pragma unroll
            for (int a = 0; a < TILE; a++) {
                float4 xv = *(const float4*)(xs + a * 256 + k);
                acc[a] = fmaf(xv.x, w0, acc[a]); acc[a] = fmaf(xv.y, w1, acc[a]);
                acc[a] = fmaf(xv.z, w2, acc[a]); acc[a] = fmaf(xv.w, w3, acc[a]);
            }
        }
        for (int a = 0; a < nt; a++) {
            float val = fmaxf(acc[a] + b, 0.f);
            val = fmaf(scale, val - m, bb);
            sum += val; mx = fmaxf(mx, val);
        }
    }
    fp[(size_t)seg * 1024 + c] = tanhf(sum);
    fp[(size_t)seg * 1024 + 512 + c] = tanhf(mx);
}

// Head: logits = fp @ head_W + head_b; paired 2-class softmax.
__global__ __launch_bounds__(256) void head_kernel(
    const float* __restrict__ fp,     // (1024, 1024)
    const float* __restrict__ hW,     // (1024, 24)
    const float* __restrict__ hb,     // (24,)
    float* __restrict__ logits,       // (1024, 24)
    float* __restrict__ probs)        // (1024, 24)
{
    __shared__ float fps[1024];
    int s = blockIdx.x;
    for (int i = threadIdx.x; i < 1024; i += 256) fps[i] = fp[(size_t)s * 1024 + i];
    __syncthreads();
    if (threadIdx.x >= 64) return;    // wave 0 only past this point
    int o = threadIdx.x;
    float acc = 0.f;
    if (o < 24) {
        acc = hb[o];
#pragma unroll 4
        for (int k = 0; k < 1024; k++) acc = fmaf(fps[k], hW[k * 24 + o], acc);
    }
    float accn = __shfl_down(acc, 1);
    if (o < 24) {
        logits[(size_t)s * 24 + o] = acc;
        if ((o & 1) == 0) {
            float p0 = 1.f / (1.f + expf(accn - acc));
            float p1 = 1.f / (1.f + expf(acc - accn));
            probs[(size_t)s * 24 + o] = p0;
            probs[(size_t)s * 24 + o + 1] = p1;
        }
    }
}

extern "C" void kernel_launch(void* const* d_in, const int* in_sizes, int n_in,
                              void* d_out, int out_size, void* d_ws, size_t ws_size,
                              hipStream_t stream) {
    const float* atom_features = (const float*)d_in[0];
    const int*   membership    = (const int*)d_in[2];
    const int*   a1 = (const int*)d_in[4];
    const int*   a2 = (const int*)d_in[5];
    const int*   a3 = (const int*)d_in[6];
    const int*   a4 = (const int*)d_in[7];
    const float* gc1W = (const float*)d_in[8];
    const float* gc1b = (const float*)d_in[9];
    const float* gc2W = (const float*)d_in[10];
    const float* gc2b = (const float*)d_in[11];
    const float* bn1  = (const float*)d_in[12];
    const float* bn2  = (const float*)d_in[13];
    const float* bn3  = (const float*)d_in[14];
    const float* dW   = (const float*)d_in[15];
    const float* db   = (const float*)d_in[16];
    const float* hW   = (const float*)d_in[17];
    const float* hb   = (const float*)d_in[18];

    float* out    = (float*)d_out;
    float* probs  = out;               // 1024*24
    float* logits = out + 24576;       // 1024*24
    float* fp     = out + 49152;       // 1024*1024

    float* bufA  = (float*)d_ws;                       // NA*256 floats
    float* bufB  = bufA + (size_t)NA * 256;            // NA*256 floats
    int*   count = (int*)(bufB + (size_t)NA * 256);    // 1024
    int*   list  = count + 1024;                       // 1024*MAXSEG

    zero_count_kernel<<<4, 256, 0, stream>>>(count);
    bucket_kernel<<<256, 256, 0, stream>>>(membership, count, list);
    conv_kernel<75><<<4096, 256, 0, stream>>>(atom_features, a1, a2, a3, a4,
                                              gc1W, gc1b, bn1, bufA);
    pool_kernel<<<16384, 256, 0, stream>>>(bufA, a1, a2, a3, a4, bufB);
    conv_kernel<256><<<4096, 256, 0, stream>>>(bufB, a1, a2, a3, a4,
                                               gc2W, gc2b, bn2, bufA);
    pool_kernel<<<16384, 256, 0, stream>>>(bufA, a1, a2, a3, a4, bufB);
    dense_seg_kernel<<<1024, 512, 0, stream>>>(bufB, dW, db, bn3, count, list, fp);
    head_kernel<<<1024, 256, 0, stream>>>(fp, hW, hb, logits, probs);
}

// Round 2
// 430.052 us; speedup vs baseline: 2.7152x; 2.7152x over previous
//
#include <hip/hip_runtime.h>
#include <hip/hip_bf16.h>
#include <math.h>

#define NA 65536
#define MAXSEG 160

typedef _Float16 half8 __attribute__((ext_vector_type(8)));
typedef _Float16 h4    __attribute__((ext_vector_type(4)));
typedef float float4v  __attribute__((ext_vector_type(4)));

// segment starts: 0, 4096, 16384, 36864, 57344 (all multiples of 128)

__device__ __forceinline__ void atom_seg(int atom, int& d, int& loc,
                                         const int* a1, const int* a2,
                                         const int* a3, const int* a4,
                                         const int*& adj) {
    if (atom < 4096)       { d = 0; loc = 0; adj = nullptr; }
    else if (atom < 16384) { d = 1; adj = a1; loc = atom - 4096; }
    else if (atom < 36864) { d = 2; adj = a2; loc = atom - 16384; }
    else if (atom < 57344) { d = 3; adj = a3; loc = atom - 36864; }
    else                   { d = 4; adj = a4; loc = atom - 57344; }
}

__global__ void zero_count_kernel(int* __restrict__ count) {
    int i = blockIdx.x * 256 + threadIdx.x;
    if (i < 1024) count[i] = 0;
}

__global__ void bucket_kernel(const int* __restrict__ mem, int* __restrict__ count,
                              int* __restrict__ list) {
    int i = blockIdx.x * 256 + threadIdx.x;
    int seg = mem[i];
    int pos = atomicAdd(&count[seg], 1);
    if (pos < MAXSEG) list[seg * MAXSEG + pos] = i;
}

// ---- weight conversion -------------------------------------------------
// Wc1[seg][n][k] (5,256,160): k<75 self W, 75..149 neigh W, 150..159 zero
__global__ void cvt_w1_kernel(const float* __restrict__ gc1W, const float* __restrict__ gc1b,
                              _Float16* __restrict__ Wc1, float* __restrict__ bias1) {
    int idx = blockIdx.x * 256 + threadIdx.x;       // 204800
    if (idx < 204800) {
        int k = idx % 160, n = (idx / 160) & 255, seg = idx / (160 * 256);
        float v = 0.f;
        if (k < 75) { int w = (seg == 0) ? 8 : (2 * seg - 1); v = gc1W[(w * 75 + k) * 256 + n]; }
        else if (k < 150 && seg > 0) { int w = 2 * (seg - 1); v = gc1W[(w * 75 + (k - 75)) * 256 + n]; }
        Wc1[(size_t)(seg * 256 + n) * 160 + k] = (_Float16)v;
    }
    if (idx < 1280) {
        int n = idx & 255, seg = idx >> 8;
        bias1[idx] = (seg == 0) ? gc1b[8 * 256 + n]
                                : gc1b[(2 * seg - 1) * 256 + n] + gc1b[2 * (seg - 1) * 256 + n];
    }
}

// Wc2[seg][n][k] (5,256,512): k<256 self, 256..511 neigh
__global__ void cvt_w2_kernel(const float* __restrict__ gc2W, const float* __restrict__ gc2b,
                              _Float16* __restrict__ Wc2, float* __restrict__ bias2) {
    int idx = blockIdx.x * 256 + threadIdx.x;       // 655360
    if (idx < 655360) {
        int k = idx & 511, n = (idx >> 9) & 255, seg = idx >> 17;
        float v = 0.f;
        if (k < 256) { int w = (seg == 0) ? 8 : (2 * seg - 1); v = gc2W[(w * 256 + k) * 256 + n]; }
        else if (seg > 0) { int w = 2 * (seg - 1); v = gc2W[(w * 256 + (k - 256)) * 256 + n]; }
        Wc2[(size_t)(seg * 256 + n) * 512 + k] = (_Float16)v;
    }
    if (idx < 1280) {
        int n = idx & 255, seg = idx >> 8;
        bias2[idx] = (seg == 0) ? gc2b[8 * 256 + n]
                                : gc2b[(2 * seg - 1) * 256 + n] + gc2b[2 * (seg - 1) * 256 + n];
    }
}

// dWt[n][k] (512,256) = dW[k][n]
__global__ void cvt_wd_kernel(const float* __restrict__ dW, _Float16* __restrict__ dWt) {
    int idx = blockIdx.x * 256 + threadIdx.x;       // 131072
    int n = idx >> 8, k = idx & 255;
    dWt[(size_t)n * 256 + k] = (_Float16)dW[(size_t)k * 512 + n];
}

// ---- gathers -----------------------------------------------------------
// X1 (NA,160) f16 = [af(75) | sum-neigh af(75) | 0(10)]
__global__ __launch_bounds__(256) void gather1_kernel(
    const float* __restrict__ af,
    const int* __restrict__ a1, const int* __restrict__ a2,
    const int* __restrict__ a3, const int* __restrict__ a4,
    _Float16* __restrict__ X1) {
    int atom = blockIdx.x * 4 + (threadIdx.x >> 6);
    int lane = threadIdx.x & 63;
    int d, loc; const int* adj;
    atom_seg(atom, d, loc, a1, a2, a3, a4, adj);
    int nb[4];
    for (int j = 0; j < d; j++) nb[j] = adj[(size_t)loc * d + j];
    for (int k = lane; k < 75; k += 64) {
        X1[(size_t)atom * 160 + k] = (_Float16)af[(size_t)atom * 75 + k];
        float s = 0.f;
        for (int j = 0; j < d; j++) s += af[(size_t)nb[j] * 75 + k];
        X1[(size_t)atom * 160 + 75 + k] = (_Float16)s;
    }
    if (lane < 10) X1[(size_t)atom * 160 + 150 + lane] = (_Float16)0.f;
}

// X2 (NA,512) f16 = [p(256) | sum-neigh p(256)]
__global__ __launch_bounds__(256) void gather2_kernel(
    const _Float16* __restrict__ p,
    const int* __restrict__ a1, const int* __restrict__ a2,
    const int* __restrict__ a3, const int* __restrict__ a4,
    _Float16* __restrict__ X2) {
    int atom = blockIdx.x * 4 + (threadIdx.x >> 6);
    int lane = threadIdx.x & 63;
    int d, loc; const int* adj;
    atom_seg(atom, d, loc, a1, a2, a3, a4, adj);
    int nb[4];
    for (int j = 0; j < d; j++) nb[j] = adj[(size_t)loc * d + j];
    h4 self = *(const h4*)(p + (size_t)atom * 256 + lane * 4);
    *(h4*)(X2 + (size_t)atom * 512 + lane * 4) = self;
    float s0 = 0.f, s1 = 0.f, s2 = 0.f, s3 = 0.f;
    for (int j = 0; j < d; j++) {
        h4 v = *(const h4*)(p + (size_t)nb[j] * 256 + lane * 4);
        s0 += (float)v[0]; s1 += (float)v[1]; s2 += (float)v[2]; s3 += (float)v[3];
    }
    h4 o; o[0] = (_Float16)s0; o[1] = (_Float16)s1; o[2] = (_Float16)s2; o[3] = (_Float16)s3;
    *(h4*)(X2 + (size_t)atom * 512 + 256 + lane * 4) = o;
}

// ---- MFMA GEMM: out(f16, M x N) = relu(X @ Wt^T + bias) -> BN ----------
// X (NA,K) f16 row-major; Wt (n-major: [seg][n][k]) f16; per-128-row-tile
// segment selects W slice (wstride=0 for dense).
template<int K, int N>
__global__ __launch_bounds__(256) void gemm_kernel(
    const _Float16* __restrict__ X, const _Float16* __restrict__ Wt,
    const float* __restrict__ bias, const float* __restrict__ bnp,
    int wstride, int bstride, _Float16* __restrict__ out) {
    __shared__ _Float16 As[128 * 40];
    __shared__ _Float16 Bs[128 * 40];
    int m0 = blockIdx.x * 128, n0 = blockIdx.y * 128;
    int t = m0 >> 7;
    int seg = (t < 32) ? 0 : (t < 128) ? 1 : (t < 288) ? 2 : (t < 448) ? 3 : 4;
    const _Float16* Wb = Wt + (size_t)seg * wstride;
    const float* bia = bias + seg * bstride;
    int tid = threadIdx.x, lane = tid & 63, wave = tid >> 6;
    int wm = (wave >> 1) * 64, wn = (wave & 1) * 64;
    int lrow = lane & 15, lq = lane >> 4;
    float4v acc[4][4] = {};
    for (int kc = 0; kc < K / 32; kc++) {
        #pragma unroll
        for (int p = tid; p < 512; p += 256) {
            int row = p >> 2, cch = p & 3;
            *(uint4*)(As + row * 40 + cch * 8) =
                *(const uint4*)(X + (size_t)(m0 + row) * K + kc * 32 + cch * 8);
            *(uint4*)(Bs + row * 40 + cch * 8) =
                *(const uint4*)(Wb + (size_t)(n0 + row) * K + kc * 32 + cch * 8);
        }
        __syncthreads();
        half8 af[4], bf[4];
        #pragma unroll
        for (int i = 0; i < 4; i++) {
            af[i] = *(const half8*)(As + (wm + i * 16 + lrow) * 40 + lq * 8);
            bf[i] = *(const half8*)(Bs + (wn + i * 16 + lrow) * 40 + lq * 8);
        }
        #pragma unroll
        for (int mi = 0; mi < 4; mi++)
            #pragma unroll
            for (int ni = 0; ni < 4; ni++)
                acc[mi][ni] = __builtin_amdgcn_mfma_f32_16x16x32_f16(af[mi], bf[ni], acc[mi][ni], 0, 0, 0);
        __syncthreads();
    }
    #pragma unroll
    for (int ni = 0; ni < 4; ni++) {
        int col = n0 + wn + ni * 16 + lrow;
        float bv = bia[col], g = bnp[col], be = bnp[N + col];
        float mn = bnp[2 * N + col], vr = bnp[3 * N + col];
        float sc = g * rsqrtf(vr + 1e-3f);
        #pragma unroll
        for (int mi = 0; mi < 4; mi++) {
            int rbase = m0 + wm + mi * 16 + lq * 4;
            #pragma unroll
            for (int r = 0; r < 4; r++) {
                float v = acc[mi][ni][r] + bv;
                v = fmaxf(v, 0.f);
                v = sc * (v - mn) + be;
                out[(size_t)(rbase + r) * N + col] = (_Float16)v;
            }
        }
    }
}

// ---- pool (f16): per atom elementwise max over {self, neighbors} -------
__global__ __launch_bounds__(256) void pool_f16_kernel(
    const _Float16* __restrict__ x,
    const int* __restrict__ a1, const int* __restrict__ a2,
    const int* __restrict__ a3, const int* __restrict__ a4,
    _Float16* __restrict__ out) {
    int atom = blockIdx.x * 4 + (threadIdx.x >> 6);
    int lane = threadIdx.x & 63;
    int d, loc; const int* adj;
    atom_seg(atom, d, loc, a1, a2, a3, a4, adj);
    h4 m = *(const h4*)(x + (size_t)atom * 256 + lane * 4);
    float m0 = (float)m[0], m1 = (float)m[1], m2 = (float)m[2], m3 = (float)m[3];
    for (int j = 0; j < d; j++) {
        int nb = adj[(size_t)loc * d + j];
        h4 v = *(const h4*)(x + (size_t)nb * 256 + lane * 4);
        m0 = fmaxf(m0, (float)v[0]); m1 = fmaxf(m1, (float)v[1]);
        m2 = fmaxf(m2, (float)v[2]); m3 = fmaxf(m3, (float)v[3]);
    }
    h4 o; o[0] = (_Float16)m0; o[1] = (_Float16)m1; o[2] = (_Float16)m2; o[3] = (_Float16)m3;
    *(h4*)(out + (size_t)atom * 256 + lane * 4) = o;
}

// ---- segment reduce: fp = tanh([seg_sum(h) | seg_max(h)]) --------------
__global__ __launch_bounds__(512) void seg_reduce_kernel(
    const _Float16* __restrict__ h, const int* __restrict__ count,
    const int* __restrict__ list, float* __restrict__ fp) {
    int seg = blockIdx.x, c = threadIdx.x;
    int n = count[seg]; if (n > MAXSEG) n = MAXSEG;
    float sum = 0.f, mx = -INFINITY;
    for (int a = 0; a < n; a++) {
        int row = list[seg * MAXSEG + a];
        float v = (float)h[(size_t)row * 512 + c];
        sum += v; mx = fmaxf(mx, v);
    }
    fp[(size_t)seg * 1024 + c] = tanhf(sum);
    fp[(size_t)seg * 1024 + 512 + c] = tanhf(mx);
}

// ---- head --------------------------------------------------------------
__global__ __launch_bounds__(256) void head_kernel(
    const float* __restrict__ fp, const float* __restrict__ hW,
    const float* __restrict__ hb, float* __restrict__ logits,
    float* __restrict__ probs) {
    __shared__ float fps[1024];
    int s = blockIdx.x;
    for (int i = threadIdx.x; i < 1024; i += 256) fps[i] = fp[(size_t)s * 1024 + i];
    __syncthreads();
    if (threadIdx.x >= 64) return;
    int o = threadIdx.x;
    float acc = 0.f;
    if (o < 24) {
        acc = hb[o];
#pragma unroll 4
        for (int k = 0; k < 1024; k++) acc = fmaf(fps[k], hW[k * 24 + o], acc);
    }
    float accn = __shfl_down(acc, 1);
    if (o < 24) {
        logits[(size_t)s * 24 + o] = acc;
        if ((o & 1) == 0) {
            probs[(size_t)s * 24 + o] = 1.f / (1.f + expf(accn - acc));
            probs[(size_t)s * 24 + o + 1] = 1.f / (1.f + expf(acc - accn));
        }
    }
}

extern "C" void kernel_launch(void* const* d_in, const int* in_sizes, int n_in,
                              void* d_out, int out_size, void* d_ws, size_t ws_size,
                              hipStream_t stream) {
    const float* af         = (const float*)d_in[0];
    const int*   membership = (const int*)d_in[2];
    const int*   a1 = (const int*)d_in[4];
    const int*   a2 = (const int*)d_in[5];
    const int*   a3 = (const int*)d_in[6];
    const int*   a4 = (const int*)d_in[7];
    const float* gc1W = (const float*)d_in[8];
    const float* gc1b = (const float*)d_in[9];
    const float* gc2W = (const float*)d_in[10];
    const float* gc2b = (const float*)d_in[11];
    const float* bn1  = (const float*)d_in[12];
    const float* bn2  = (const float*)d_in[13];
    const float* bn3  = (const float*)d_in[14];
    const float* dW   = (const float*)d_in[15];
    const float* db   = (const float*)d_in[16];
    const float* hW   = (const float*)d_in[17];
    const float* hb   = (const float*)d_in[18];

    float* out    = (float*)d_out;
    float* probs  = out;
    float* logits = out + 24576;
    float* fp     = out + 49152;

    _Float16* Wc1  = (_Float16*)d_ws;                 // 5*256*160 = 204800
    _Float16* Wc2  = Wc1 + 204800;                    // 5*256*512 = 655360
    _Float16* dWt  = Wc2 + 655360;                    // 512*256   = 131072
    float* bias1   = (float*)(dWt + 131072);          // 1280
    float* bias2   = bias1 + 1280;                    // 1280
    int* count     = (int*)(bias2 + 1280);            // 1024
    int* list      = count + 1024;                    // 163840
    _Float16* bufBig = (_Float16*)(list + 163840);    // NA*512 (X1 / X2 / h)
    _Float16* bufY   = bufBig + (size_t)NA * 512;     // NA*256
    _Float16* bufP   = bufY + (size_t)NA * 256;       // NA*256

    zero_count_kernel<<<4, 256, 0, stream>>>(count);
    bucket_kernel<<<256, 256, 0, stream>>>(membership, count, list);
    cvt_w1_kernel<<<800, 256, 0, stream>>>(gc1W, gc1b, Wc1, bias1);
    cvt_w2_kernel<<<2560, 256, 0, stream>>>(gc2W, gc2b, Wc2, bias2);
    cvt_wd_kernel<<<512, 256, 0, stream>>>(dW, dWt);

    gather1_kernel<<<16384, 256, 0, stream>>>(af, a1, a2, a3, a4, bufBig);
    gemm_kernel<160, 256><<<dim3(512, 2), 256, 0, stream>>>(bufBig, Wc1, bias1, bn1,
                                                            256 * 160, 256, bufY);
    pool_f16_kernel<<<16384, 256, 0, stream>>>(bufY, a1, a2, a3, a4, bufP);
    gather2_kernel<<<16384, 256, 0, stream>>>(bufP, a1, a2, a3, a4, bufBig);
    gemm_kernel<512, 256><<<dim3(512, 2), 256, 0, stream>>>(bufBig, Wc2, bias2, bn2,
                                                            256 * 512, 256, bufY);
    pool_f16_kernel<<<16384, 256, 0, stream>>>(bufY, a1, a2, a3, a4, bufP);
    gemm_kernel<256, 512><<<dim3(512, 4), 256, 0, stream>>>(bufP, dWt, db, bn3,
                                                            0, 0, bufBig);
    seg_reduce_kernel<<<1024, 512, 0, stream>>>(bufBig, count, list, fp);
    head_kernel<<<1024, 256, 0, stream>>>(fp, hW, hb, logits, probs);
}

// Round 3
// 378.893 us; speedup vs baseline: 3.0818x; 1.1350x over previous
//
#include <hip/hip_runtime.h>
#include <hip/hip_bf16.h>
#include <math.h>

#define NA 65536
#define MAXSEG 160

typedef _Float16 half8 __attribute__((ext_vector_type(8)));
typedef _Float16 h4    __attribute__((ext_vector_type(4)));
typedef float float4v  __attribute__((ext_vector_type(4)));

// segment starts: 0, 4096, 16384, 36864, 57344 (all multiples of 128)

__device__ __forceinline__ void atom_seg(int atom, int& d, int& loc,
                                         const int* a1, const int* a2,
                                         const int* a3, const int* a4,
                                         const int*& adj) {
    if (atom < 4096)       { d = 0; loc = 0; adj = nullptr; }
    else if (atom < 16384) { d = 1; adj = a1; loc = atom - 4096; }
    else if (atom < 36864) { d = 2; adj = a2; loc = atom - 16384; }
    else if (atom < 57344) { d = 3; adj = a3; loc = atom - 36864; }
    else                   { d = 4; adj = a4; loc = atom - 57344; }
}

__global__ void zero_count_kernel(int* __restrict__ count) {
    int i = blockIdx.x * 256 + threadIdx.x;
    if (i < 1024) count[i] = 0;
}

__global__ void bucket_kernel(const int* __restrict__ mem, int* __restrict__ count,
                              int* __restrict__ list) {
    int i = blockIdx.x * 256 + threadIdx.x;
    int seg = mem[i];
    int pos = atomicAdd(&count[seg], 1);
    if (pos < MAXSEG) list[seg * MAXSEG + pos] = i;
}

// ---- weight conversion -------------------------------------------------
// Wc1[seg][n][k] (5,256,160): k<75 self W, 75..149 neigh W, 150..159 zero
__global__ void cvt_w1_kernel(const float* __restrict__ gc1W, const float* __restrict__ gc1b,
                              _Float16* __restrict__ Wc1, float* __restrict__ bias1) {
    int idx = blockIdx.x * 256 + threadIdx.x;       // 204800
    if (idx < 204800) {
        int k = idx % 160, n = (idx / 160) & 255, seg = idx / (160 * 256);
        float v = 0.f;
        if (k < 75) { int w = (seg == 0) ? 8 : (2 * seg - 1); v = gc1W[(w * 75 + k) * 256 + n]; }
        else if (k < 150 && seg > 0) { int w = 2 * (seg - 1); v = gc1W[(w * 75 + (k - 75)) * 256 + n]; }
        Wc1[(size_t)(seg * 256 + n) * 160 + k] = (_Float16)v;
    }
    if (idx < 1280) {
        int n = idx & 255, seg = idx >> 8;
        bias1[idx] = (seg == 0) ? gc1b[8 * 256 + n]
                                : gc1b[(2 * seg - 1) * 256 + n] + gc1b[2 * (seg - 1) * 256 + n];
    }
}

// Wc2[seg][n][k] (5,256,512): k<256 self, 256..511 neigh
__global__ void cvt_w2_kernel(const float* __restrict__ gc2W, const float* __restrict__ gc2b,
                              _Float16* __restrict__ Wc2, float* __restrict__ bias2) {
    int idx = blockIdx.x * 256 + threadIdx.x;       // 655360
    if (idx < 655360) {
        int k = idx & 511, n = (idx >> 9) & 255, seg = idx >> 17;
        float v = 0.f;
        if (k < 256) { int w = (seg == 0) ? 8 : (2 * seg - 1); v = gc2W[(w * 256 + k) * 256 + n]; }
        else if (seg > 0) { int w = 2 * (seg - 1); v = gc2W[(w * 256 + (k - 256)) * 256 + n]; }
        Wc2[(size_t)(seg * 256 + n) * 512 + k] = (_Float16)v;
    }
    if (idx < 1280) {
        int n = idx & 255, seg = idx >> 8;
        bias2[idx] = (seg == 0) ? gc2b[8 * 256 + n]
                                : gc2b[(2 * seg - 1) * 256 + n] + gc2b[2 * (seg - 1) * 256 + n];
    }
}

// dWt[n][k] (512,256) = dW[k][n]
__global__ void cvt_wd_kernel(const float* __restrict__ dW, _Float16* __restrict__ dWt) {
    int idx = blockIdx.x * 256 + threadIdx.x;       // 131072
    int n = idx >> 8, k = idx & 255;
    dWt[(size_t)n * 256 + k] = (_Float16)dW[(size_t)k * 512 + n];
}

// hWt[o][k] (24,1024) = hW[k][o]
__global__ void cvt_hw_kernel(const float* __restrict__ hW, float* __restrict__ hWt) {
    int idx = blockIdx.x * 256 + threadIdx.x;       // 24576
    int o = idx / 1024, k = idx & 1023;
    hWt[idx] = hW[k * 24 + o];
}

// ---- gathers -----------------------------------------------------------
// X1 (NA,160) f16 = [af(75) | sum-neigh af(75) | 0(10)]
__global__ __launch_bounds__(256) void gather1_kernel(
    const float* __restrict__ af,
    const int* __restrict__ a1, const int* __restrict__ a2,
    const int* __restrict__ a3, const int* __restrict__ a4,
    _Float16* __restrict__ X1) {
    int atom = blockIdx.x * 4 + (threadIdx.x >> 6);
    int lane = threadIdx.x & 63;
    int d, loc; const int* adj;
    atom_seg(atom, d, loc, a1, a2, a3, a4, adj);
    int nb[4];
    for (int j = 0; j < d; j++) nb[j] = adj[(size_t)loc * d + j];
    for (int k = lane; k < 75; k += 64) {
        X1[(size_t)atom * 160 + k] = (_Float16)af[(size_t)atom * 75 + k];
        float s = 0.f;
        for (int j = 0; j < d; j++) s += af[(size_t)nb[j] * 75 + k];
        X1[(size_t)atom * 160 + 75 + k] = (_Float16)s;
    }
    if (lane < 10) X1[(size_t)atom * 160 + 150 + lane] = (_Float16)0.f;
}

// X2 (NA,512) f16 = [p(256) | sum-neigh p(256)]
__global__ __launch_bounds__(256) void gather2_kernel(
    const _Float16* __restrict__ p,
    const int* __restrict__ a1, const int* __restrict__ a2,
    const int* __restrict__ a3, const int* __restrict__ a4,
    _Float16* __restrict__ X2) {
    int atom = blockIdx.x * 4 + (threadIdx.x >> 6);
    int lane = threadIdx.x & 63;
    int d, loc; const int* adj;
    atom_seg(atom, d, loc, a1, a2, a3, a4, adj);
    int nb[4];
    for (int j = 0; j < d; j++) nb[j] = adj[(size_t)loc * d + j];
    h4 self = *(const h4*)(p + (size_t)atom * 256 + lane * 4);
    *(h4*)(X2 + (size_t)atom * 512 + lane * 4) = self;
    float s0 = 0.f, s1 = 0.f, s2 = 0.f, s3 = 0.f;
    for (int j = 0; j < d; j++) {
        h4 v = *(const h4*)(p + (size_t)nb[j] * 256 + lane * 4);
        s0 += (float)v[0]; s1 += (float)v[1]; s2 += (float)v[2]; s3 += (float)v[3];
    }
    h4 o; o[0] = (_Float16)s0; o[1] = (_Float16)s1; o[2] = (_Float16)s2; o[3] = (_Float16)s3;
    *(h4*)(X2 + (size_t)atom * 512 + 256 + lane * 4) = o;
}

// ---- MFMA GEMM: out(f16, M x N) = relu(X @ Wt^T + bias) -> BN ----------
template<int K, int N>
__global__ __launch_bounds__(256) void gemm_kernel(
    const _Float16* __restrict__ X, const _Float16* __restrict__ Wt,
    const float* __restrict__ bias, const float* __restrict__ bnp,
    int wstride, int bstride, _Float16* __restrict__ out) {
    __shared__ _Float16 As[128 * 40];
    __shared__ _Float16 Bs[128 * 40];
    int m0 = blockIdx.x * 128, n0 = blockIdx.y * 128;
    int t = m0 >> 7;
    int seg = (t < 32) ? 0 : (t < 128) ? 1 : (t < 288) ? 2 : (t < 448) ? 3 : 4;
    const _Float16* Wb = Wt + (size_t)seg * wstride;
    const float* bia = bias + seg * bstride;
    int tid = threadIdx.x, lane = tid & 63, wave = tid >> 6;
    int wm = (wave >> 1) * 64, wn = (wave & 1) * 64;
    int lrow = lane & 15, lq = lane >> 4;
    float4v acc[4][4] = {};
    for (int kc = 0; kc < K / 32; kc++) {
        #pragma unroll
        for (int p = tid; p < 512; p += 256) {
            int row = p >> 2, cch = p & 3;
            *(uint4*)(As + row * 40 + cch * 8) =
                *(const uint4*)(X + (size_t)(m0 + row) * K + kc * 32 + cch * 8);
            *(uint4*)(Bs + row * 40 + cch * 8) =
                *(const uint4*)(Wb + (size_t)(n0 + row) * K + kc * 32 + cch * 8);
        }
        __syncthreads();
        half8 af[4], bf[4];
        #pragma unroll
        for (int i = 0; i < 4; i++) {
            af[i] = *(const half8*)(As + (wm + i * 16 + lrow) * 40 + lq * 8);
            bf[i] = *(const half8*)(Bs + (wn + i * 16 + lrow) * 40 + lq * 8);
        }
        #pragma unroll
        for (int mi = 0; mi < 4; mi++)
            #pragma unroll
            for (int ni = 0; ni < 4; ni++)
                acc[mi][ni] = __builtin_amdgcn_mfma_f32_16x16x32_f16(af[mi], bf[ni], acc[mi][ni], 0, 0, 0);
        __syncthreads();
    }
    #pragma unroll
    for (int ni = 0; ni < 4; ni++) {
        int col = n0 + wn + ni * 16 + lrow;
        float bv = bia[col], g = bnp[col], be = bnp[N + col];
        float mn = bnp[2 * N + col], vr = bnp[3 * N + col];
        float sc = g * rsqrtf(vr + 1e-3f);
        #pragma unroll
        for (int mi = 0; mi < 4; mi++) {
            int rbase = m0 + wm + mi * 16 + lq * 4;
            #pragma unroll
            for (int r = 0; r < 4; r++) {
                float v = acc[mi][ni][r] + bv;
                v = fmaxf(v, 0.f);
                v = sc * (v - mn) + be;
                out[(size_t)(rbase + r) * N + col] = (_Float16)v;
            }
        }
    }
}

// ---- pool (f16): per atom elementwise max over {self, neighbors} -------
__global__ __launch_bounds__(256) void pool_f16_kernel(
    const _Float16* __restrict__ x,
    const int* __restrict__ a1, const int* __restrict__ a2,
    const int* __restrict__ a3, const int* __restrict__ a4,
    _Float16* __restrict__ out) {
    int atom = blockIdx.x * 4 + (threadIdx.x >> 6);
    int lane = threadIdx.x & 63;
    int d, loc; const int* adj;
    atom_seg(atom, d, loc, a1, a2, a3, a4, adj);
    h4 m = *(const h4*)(x + (size_t)atom * 256 + lane * 4);
    float m0 = (float)m[0], m1 = (float)m[1], m2 = (float)m[2], m3 = (float)m[3];
    for (int j = 0; j < d; j++) {
        int nb = adj[(size_t)loc * d + j];
        h4 v = *(const h4*)(x + (size_t)nb * 256 + lane * 4);
        m0 = fmaxf(m0, (float)v[0]); m1 = fmaxf(m1, (float)v[1]);
        m2 = fmaxf(m2, (float)v[2]); m3 = fmaxf(m3, (float)v[3]);
    }
    h4 o; o[0] = (_Float16)m0; o[1] = (_Float16)m1; o[2] = (_Float16)m2; o[3] = (_Float16)m3;
    *(h4*)(out + (size_t)atom * 256 + lane * 4) = o;
}

// ---- segment reduce: fp = tanh([seg_sum(h) | seg_max(h)]) --------------
__global__ __launch_bounds__(512) void seg_reduce_kernel(
    const _Float16* __restrict__ h, const int* __restrict__ count,
    const int* __restrict__ list, float* __restrict__ fp) {
    int seg = blockIdx.x, c = threadIdx.x;
    int n = count[seg]; if (n > MAXSEG) n = MAXSEG;
    float sum = 0.f, mx = -INFINITY;
    for (int a = 0; a < n; a++) {
        int row = list[seg * MAXSEG + a];
        float v = (float)h[(size_t)row * 512 + c];
        sum += v; mx = fmaxf(mx, v);
    }
    fp[(size_t)seg * 1024 + c] = tanhf(sum);
    fp[(size_t)seg * 1024 + 512 + c] = tanhf(mx);
}

// ---- head: all 256 threads active, k-split 8-way, hWt streamed ---------
__global__ __launch_bounds__(256) void head_kernel(
    const float* __restrict__ fp, const float* __restrict__ hWt,
    const float* __restrict__ hb, float* __restrict__ logits,
    float* __restrict__ probs) {
    __shared__ float fps[1024];
    __shared__ float red[32];
    int s = blockIdx.x;
    for (int i = threadIdx.x; i < 1024; i += 256) fps[i] = fp[(size_t)s * 1024 + i];
    __syncthreads();
    int t = threadIdx.x;
    int o = t >> 3, kp = t & 7;      // o 0..31 (24 active), kp 0..7
    float acc = 0.f;
    if (o < 24) {
        const float* w = hWt + (size_t)o * 1024 + kp * 128;
        const float* f = fps + kp * 128;
        #pragma unroll 8
        for (int i = 0; i < 128; i++) acc = fmaf(f[i], w[i], acc);
    }
    // reduce across the 8 kp lanes (contiguous within a wave)
    acc += __shfl_down(acc, 4, 64);
    acc += __shfl_down(acc, 2, 64);
    acc += __shfl_down(acc, 1, 64);
    if (o < 24 && kp == 0) red[o] = acc + hb[o];
    __syncthreads();
    if (t < 24) {
        float a = red[t];
        float an = red[t ^ 1];
        logits[(size_t)s * 24 + t] = a;
        probs[(size_t)s * 24 + t] = 1.f / (1.f + expf(an - a));
    }
}

extern "C" void kernel_launch(void* const* d_in, const int* in_sizes, int n_in,
                              void* d_out, int out_size, void* d_ws, size_t ws_size,
                              hipStream_t stream) {
    const float* af         = (const float*)d_in[0];
    const int*   membership = (const int*)d_in[2];
    const int*   a1 = (const int*)d_in[4];
    const int*   a2 = (const int*)d_in[5];
    const int*   a3 = (const int*)d_in[6];
    const int*   a4 = (const int*)d_in[7];
    const float* gc1W = (const float*)d_in[8];
    const float* gc1b = (const float*)d_in[9];
    const float* gc2W = (const float*)d_in[10];
    const float* gc2b = (const float*)d_in[11];
    const float* bn1  = (const float*)d_in[12];
    const float* bn2  = (const float*)d_in[13];
    const float* bn3  = (const float*)d_in[14];
    const float* dW   = (const float*)d_in[15];
    const float* db   = (const float*)d_in[16];
    const float* hW   = (const float*)d_in[17];
    const float* hb   = (const float*)d_in[18];

    float* out    = (float*)d_out;
    float* probs  = out;
    float* logits = out + 24576;
    float* fp     = out + 49152;

    _Float16* Wc1  = (_Float16*)d_ws;                 // 5*256*160 = 204800
    _Float16* Wc2  = Wc1 + 204800;                    // 5*256*512 = 655360
    _Float16* dWt  = Wc2 + 655360;                    // 512*256   = 131072
    float* bias1   = (float*)(dWt + 131072);          // 1280
    float* bias2   = bias1 + 1280;                    // 1280
    float* hWt     = bias2 + 1280;                    // 24576
    int* count     = (int*)(hWt + 24576);             // 1024
    int* list      = count + 1024;                    // 163840
    _Float16* bufBig = (_Float16*)(list + 163840);    // NA*512 (X1 / X2 / h)
    _Float16* bufY   = bufBig + (size_t)NA * 512;     // NA*256
    _Float16* bufP   = bufY + (size_t)NA * 256;       // NA*256

    zero_count_kernel<<<4, 256, 0, stream>>>(count);
    bucket_kernel<<<256, 256, 0, stream>>>(membership, count, list);
    cvt_w1_kernel<<<800, 256, 0, stream>>>(gc1W, gc1b, Wc1, bias1);
    cvt_w2_kernel<<<2560, 256, 0, stream>>>(gc2W, gc2b, Wc2, bias2);
    cvt_wd_kernel<<<512, 256, 0, stream>>>(dW, dWt);
    cvt_hw_kernel<<<96, 256, 0, stream>>>(hW, hWt);

    gather1_kernel<<<16384, 256, 0, stream>>>(af, a1, a2, a3, a4, bufBig);
    gemm_kernel<160, 256><<<dim3(512, 2), 256, 0, stream>>>(bufBig, Wc1, bias1, bn1,
                                                            256 * 160, 256, bufY);
    pool_f16_kernel<<<16384, 256, 0, stream>>>(bufY, a1, a2, a3, a4, bufP);
    gather2_kernel<<<16384, 256, 0, stream>>>(bufP, a1, a2, a3, a4, bufBig);
    gemm_kernel<512, 256><<<dim3(512, 2), 256, 0, stream>>>(bufBig, Wc2, bias2, bn2,
                                                            256 * 512, 256, bufY);
    pool_f16_kernel<<<16384, 256, 0, stream>>>(bufY, a1, a2, a3, a4, bufP);
    gemm_kernel<256, 512><<<dim3(512, 4), 256, 0, stream>>>(bufP, dWt, db, bn3,
                                                            0, 0, bufBig);
    seg_reduce_kernel<<<1024, 512, 0, stream>>>(bufBig, count, list, fp);
    head_kernel<<<1024, 256, 0, stream>>>(fp, hWt, hb, logits, probs);
}

// Round 4
// 368.736 us; speedup vs baseline: 3.1667x; 1.0275x over previous
//
#include <hip/hip_runtime.h>
#include <hip/hip_bf16.h>
#include <math.h>

#define NA 65536
#define MAXSEG 160

typedef _Float16 half8 __attribute__((ext_vector_type(8)));
typedef _Float16 h4    __attribute__((ext_vector_type(4)));
typedef float float4v  __attribute__((ext_vector_type(4)));

// segment starts: 0, 4096, 16384, 36864, 57344 (all multiples of 128)

__device__ __forceinline__ void atom_seg(int atom, int& d, int& loc,
                                         const int* a1, const int* a2,
                                         const int* a3, const int* a4,
                                         const int*& adj) {
    if (atom < 4096)       { d = 0; loc = 0; adj = nullptr; }
    else if (atom < 16384) { d = 1; adj = a1; loc = atom - 4096; }
    else if (atom < 36864) { d = 2; adj = a2; loc = atom - 16384; }
    else if (atom < 57344) { d = 3; adj = a3; loc = atom - 36864; }
    else                   { d = 4; adj = a4; loc = atom - 57344; }
}

__global__ void zero_count_kernel(int* __restrict__ count) {
    int i = blockIdx.x * 256 + threadIdx.x;
    if (i < 1024) count[i] = 0;
}

__global__ void bucket_kernel(const int* __restrict__ mem, int* __restrict__ count,
                              int* __restrict__ list) {
    int i = blockIdx.x * 256 + threadIdx.x;
    int seg = mem[i];
    int pos = atomicAdd(&count[seg], 1);
    if (pos < MAXSEG) list[seg * MAXSEG + pos] = i;
}

// ---- weight conversion -------------------------------------------------
// Wc1[seg][n][k] (5,256,160): k<75 self W, 75..149 neigh W, 150..159 zero
__global__ void cvt_w1_kernel(const float* __restrict__ gc1W, const float* __restrict__ gc1b,
                              _Float16* __restrict__ Wc1, float* __restrict__ bias1) {
    int idx = blockIdx.x * 256 + threadIdx.x;       // 204800
    if (idx < 204800) {
        int k = idx % 160, n = (idx / 160) & 255, seg = idx / (160 * 256);
        float v = 0.f;
        if (k < 75) { int w = (seg == 0) ? 8 : (2 * seg - 1); v = gc1W[(w * 75 + k) * 256 + n]; }
        else if (k < 150 && seg > 0) { int w = 2 * (seg - 1); v = gc1W[(w * 75 + (k - 75)) * 256 + n]; }
        Wc1[(size_t)(seg * 256 + n) * 160 + k] = (_Float16)v;
    }
    if (idx < 1280) {
        int n = idx & 255, seg = idx >> 8;
        bias1[idx] = (seg == 0) ? gc1b[8 * 256 + n]
                                : gc1b[(2 * seg - 1) * 256 + n] + gc1b[2 * (seg - 1) * 256 + n];
    }
}

// Wc2[seg][n][k] (5,256,512): k<256 self, 256..511 neigh
__global__ void cvt_w2_kernel(const float* __restrict__ gc2W, const float* __restrict__ gc2b,
                              _Float16* __restrict__ Wc2, float* __restrict__ bias2) {
    int idx = blockIdx.x * 256 + threadIdx.x;       // 655360
    if (idx < 655360) {
        int k = idx & 511, n = (idx >> 9) & 255, seg = idx >> 17;
        float v = 0.f;
        if (k < 256) { int w = (seg == 0) ? 8 : (2 * seg - 1); v = gc2W[(w * 256 + k) * 256 + n]; }
        else if (seg > 0) { int w = 2 * (seg - 1); v = gc2W[(w * 256 + (k - 256)) * 256 + n]; }
        Wc2[(size_t)(seg * 256 + n) * 512 + k] = (_Float16)v;
    }
    if (idx < 1280) {
        int n = idx & 255, seg = idx >> 8;
        bias2[idx] = (seg == 0) ? gc2b[8 * 256 + n]
                                : gc2b[(2 * seg - 1) * 256 + n] + gc2b[2 * (seg - 1) * 256 + n];
    }
}

// dWt[n][k] (512,256) = dW[k][n]
__global__ void cvt_wd_kernel(const float* __restrict__ dW, _Float16* __restrict__ dWt) {
    int idx = blockIdx.x * 256 + threadIdx.x;       // 131072
    int n = idx >> 8, k = idx & 255;
    dWt[(size_t)n * 256 + k] = (_Float16)dW[(size_t)k * 512 + n];
}

// hWt[o][k] (24,1024) = hW[k][o]
__global__ void cvt_hw_kernel(const float* __restrict__ hW, float* __restrict__ hWt) {
    int idx = blockIdx.x * 256 + threadIdx.x;       // 24576
    int o = idx / 1024, k = idx & 1023;
    hWt[idx] = hW[k * 24 + o];
}

// ---- gathers -----------------------------------------------------------
// X1 (NA,160) f16 = [af(75) | sum-neigh af(75) | 0(10)]
__global__ __launch_bounds__(256) void gather1_kernel(
    const float* __restrict__ af,
    const int* __restrict__ a1, const int* __restrict__ a2,
    const int* __restrict__ a3, const int* __restrict__ a4,
    _Float16* __restrict__ X1) {
    int atom = blockIdx.x * 4 + (threadIdx.x >> 6);
    int lane = threadIdx.x & 63;
    int d, loc; const int* adj;
    atom_seg(atom, d, loc, a1, a2, a3, a4, adj);
    int nb[4];
    for (int j = 0; j < d; j++) nb[j] = adj[(size_t)loc * d + j];
    for (int k = lane; k < 75; k += 64) {
        X1[(size_t)atom * 160 + k] = (_Float16)af[(size_t)atom * 75 + k];
        float s = 0.f;
        for (int j = 0; j < d; j++) s += af[(size_t)nb[j] * 75 + k];
        X1[(size_t)atom * 160 + 75 + k] = (_Float16)s;
    }
    if (lane < 10) X1[(size_t)atom * 160 + 150 + lane] = (_Float16)0.f;
}

// Xn (NA,256) f16 = sum-neigh p (zeros for degree-0 atoms)
__global__ __launch_bounds__(256) void gather2n_kernel(
    const _Float16* __restrict__ p,
    const int* __restrict__ a1, const int* __restrict__ a2,
    const int* __restrict__ a3, const int* __restrict__ a4,
    _Float16* __restrict__ Xn) {
    int atom = blockIdx.x * 4 + (threadIdx.x >> 6);
    int lane = threadIdx.x & 63;
    int d, loc; const int* adj;
    atom_seg(atom, d, loc, a1, a2, a3, a4, adj);
    int nb[4];
    for (int j = 0; j < d; j++) nb[j] = adj[(size_t)loc * d + j];
    float s0 = 0.f, s1 = 0.f, s2 = 0.f, s3 = 0.f;
    for (int j = 0; j < d; j++) {
        h4 v = *(const h4*)(p + (size_t)nb[j] * 256 + lane * 4);
        s0 += (float)v[0]; s1 += (float)v[1]; s2 += (float)v[2]; s3 += (float)v[3];
    }
    h4 o; o[0] = (_Float16)s0; o[1] = (_Float16)s1; o[2] = (_Float16)s2; o[3] = (_Float16)s3;
    *(h4*)(Xn + (size_t)atom * 256 + lane * 4) = o;
}

// ---- MFMA GEMM: out(f16, M x N) = BN(relu(X @ Wt^T + bias)) ------------
// XOR-swizzled LDS (conflict-free b128 reads/writes), BK-deep k-chunks.
// SPLIT=1: A cols 0..255 from X (stride 256), cols 256..511 from Xn.
template<int K, int N, int BK, int SPLIT>
__global__ __launch_bounds__(256) void gemm_kernel(
    const _Float16* __restrict__ X, const _Float16* __restrict__ Xn,
    const _Float16* __restrict__ Wt,
    const float* __restrict__ bias, const float* __restrict__ bnp,
    int wstride, int bstride, _Float16* __restrict__ out) {
    constexpr int NC8 = BK / 8;          // 16B chunks per row
    __shared__ _Float16 As[128 * BK];
    __shared__ _Float16 Bs[128 * BK];
    constexpr int nb = N / 128;
    int bid = blockIdx.x;
    int m0 = (bid / nb) * 128, n0 = (bid % nb) * 128;   // n-inner for A reuse
    int t = m0 >> 7;
    int seg = (t < 32) ? 0 : (t < 128) ? 1 : (t < 288) ? 2 : (t < 448) ? 3 : 4;
    const _Float16* Wb = Wt + (size_t)seg * wstride;
    const float* bia = bias + seg * bstride;
    int tid = threadIdx.x, lane = tid & 63, wave = tid >> 6;
    int wm = (wave >> 1) * 64, wn = (wave & 1) * 64;
    int lrow = lane & 15, lq = lane >> 4;
    float4v acc[4][4] = {};
    for (int kc = 0; kc < K / BK; kc++) {
        #pragma unroll
        for (int p = tid; p < 128 * NC8; p += 256) {
            int row = p / NC8, c8 = p % NC8;
            int cs = c8 ^ (row & (NC8 - 1));
            const _Float16* srcA;
            if (!SPLIT) {
                srcA = X + (size_t)(m0 + row) * K + kc * BK + c8 * 8;
            } else {
                int kcol = kc * BK + c8 * 8;
                srcA = (kcol < 256) ? X  + (size_t)(m0 + row) * 256 + kcol
                                    : Xn + (size_t)(m0 + row) * 256 + (kcol - 256);
            }
            *(uint4*)(As + row * BK + cs * 8) = *(const uint4*)srcA;
            *(uint4*)(Bs + row * BK + cs * 8) =
                *(const uint4*)(Wb + (size_t)(n0 + row) * K + kc * BK + c8 * 8);
        }
        __syncthreads();
        #pragma unroll
        for (int kl = 0; kl < BK / 32; kl++) {
            half8 af[4], bf[4];
            #pragma unroll
            for (int i = 0; i < 4; i++) {
                int ra = wm + i * 16 + lrow;
                int ca = (kl * 4 + lq) ^ (ra & (NC8 - 1));
                af[i] = *(const half8*)(As + ra * BK + ca * 8);
                int rb = wn + i * 16 + lrow;
                int cb = (kl * 4 + lq) ^ (rb & (NC8 - 1));
                bf[i] = *(const half8*)(Bs + rb * BK + cb * 8);
            }
            #pragma unroll
            for (int mi = 0; mi < 4; mi++)
                #pragma unroll
                for (int ni = 0; ni < 4; ni++)
                    acc[mi][ni] = __builtin_amdgcn_mfma_f32_16x16x32_f16(af[mi], bf[ni], acc[mi][ni], 0, 0, 0);
        }
        __syncthreads();
    }
    #pragma unroll
    for (int ni = 0; ni < 4; ni++) {
        int col = n0 + wn + ni * 16 + lrow;
        float bv = bia[col], g = bnp[col], be = bnp[N + col];
        float mn = bnp[2 * N + col], vr = bnp[3 * N + col];
        float sc = g * rsqrtf(vr + 1e-3f);
        #pragma unroll
        for (int mi = 0; mi < 4; mi++) {
            int rbase = m0 + wm + mi * 16 + lq * 4;
            #pragma unroll
            for (int r = 0; r < 4; r++) {
                float v = acc[mi][ni][r] + bv;
                v = fmaxf(v, 0.f);
                v = sc * (v - mn) + be;
                out[(size_t)(rbase + r) * N + col] = (_Float16)v;
            }
        }
    }
}

// ---- pool (f16): per atom elementwise max over {self, neighbors} -------
__global__ __launch_bounds__(256) void pool_f16_kernel(
    const _Float16* __restrict__ x,
    const int* __restrict__ a1, const int* __restrict__ a2,
    const int* __restrict__ a3, const int* __restrict__ a4,
    _Float16* __restrict__ out) {
    int atom = blockIdx.x * 4 + (threadIdx.x >> 6);
    int lane = threadIdx.x & 63;
    int d, loc; const int* adj;
    atom_seg(atom, d, loc, a1, a2, a3, a4, adj);
    h4 m = *(const h4*)(x + (size_t)atom * 256 + lane * 4);
    float m0 = (float)m[0], m1 = (float)m[1], m2 = (float)m[2], m3 = (float)m[3];
    for (int j = 0; j < d; j++) {
        int nb = adj[(size_t)loc * d + j];
        h4 v = *(const h4*)(x + (size_t)nb * 256 + lane * 4);
        m0 = fmaxf(m0, (float)v[0]); m1 = fmaxf(m1, (float)v[1]);
        m2 = fmaxf(m2, (float)v[2]); m3 = fmaxf(m3, (float)v[3]);
    }
    h4 o; o[0] = (_Float16)m0; o[1] = (_Float16)m1; o[2] = (_Float16)m2; o[3] = (_Float16)m3;
    *(h4*)(out + (size_t)atom * 256 + lane * 4) = o;
}

// ---- segment reduce: fp = tanh([seg_sum(h) | seg_max(h)]) --------------
__global__ __launch_bounds__(512) void seg_reduce_kernel(
    const _Float16* __restrict__ h, const int* __restrict__ count,
    const int* __restrict__ list, float* __restrict__ fp) {
    int seg = blockIdx.x, c = threadIdx.x;
    int n = count[seg]; if (n > MAXSEG) n = MAXSEG;
    float sum = 0.f, mx = -INFINITY;
    for (int a = 0; a < n; a++) {
        int row = list[seg * MAXSEG + a];
        float v = (float)h[(size_t)row * 512 + c];
        sum += v; mx = fmaxf(mx, v);
    }
    fp[(size_t)seg * 1024 + c] = tanhf(sum);
    fp[(size_t)seg * 1024 + 512 + c] = tanhf(mx);
}

// ---- head: all 256 threads active, k-split 8-way, hWt streamed ---------
__global__ __launch_bounds__(256) void head_kernel(
    const float* __restrict__ fp, const float* __restrict__ hWt,
    const float* __restrict__ hb, float* __restrict__ logits,
    float* __restrict__ probs) {
    __shared__ float fps[1024];
    __shared__ float red[32];
    int s = blockIdx.x;
    for (int i = threadIdx.x; i < 1024; i += 256) fps[i] = fp[(size_t)s * 1024 + i];
    __syncthreads();
    int t = threadIdx.x;
    int o = t >> 3, kp = t & 7;      // o 0..31 (24 active), kp 0..7
    float acc = 0.f;
    if (o < 24) {
        const float* w = hWt + (size_t)o * 1024 + kp * 128;
        const float* f = fps + kp * 128;
        #pragma unroll 8
        for (int i = 0; i < 128; i++) acc = fmaf(f[i], w[i], acc);
    }
    acc += __shfl_down(acc, 4, 64);
    acc += __shfl_down(acc, 2, 64);
    acc += __shfl_down(acc, 1, 64);
    if (o < 24 && kp == 0) red[o] = acc + hb[o];
    __syncthreads();
    if (t < 24) {
        float a = red[t];
        float an = red[t ^ 1];
        logits[(size_t)s * 24 + t] = a;
        probs[(size_t)s * 24 + t] = 1.f / (1.f + expf(an - a));
    }
}

extern "C" void kernel_launch(void* const* d_in, const int* in_sizes, int n_in,
                              void* d_out, int out_size, void* d_ws, size_t ws_size,
                              hipStream_t stream) {
    const float* af         = (const float*)d_in[0];
    const int*   membership = (const int*)d_in[2];
    const int*   a1 = (const int*)d_in[4];
    const int*   a2 = (const int*)d_in[5];
    const int*   a3 = (const int*)d_in[6];
    const int*   a4 = (const int*)d_in[7];
    const float* gc1W = (const float*)d_in[8];
    const float* gc1b = (const float*)d_in[9];
    const float* gc2W = (const float*)d_in[10];
    const float* gc2b = (const float*)d_in[11];
    const float* bn1  = (const float*)d_in[12];
    const float* bn2  = (const float*)d_in[13];
    const float* bn3  = (const float*)d_in[14];
    const float* dW   = (const float*)d_in[15];
    const float* db   = (const float*)d_in[16];
    const float* hW   = (const float*)d_in[17];
    const float* hb   = (const float*)d_in[18];

    float* out    = (float*)d_out;
    float* probs  = out;
    float* logits = out + 24576;
    float* fp     = out + 49152;

    _Float16* Wc1  = (_Float16*)d_ws;                 // 5*256*160 = 204800
    _Float16* Wc2  = Wc1 + 204800;                    // 5*256*512 = 655360
    _Float16* dWt  = Wc2 + 655360;                    // 512*256   = 131072
    float* bias1   = (float*)(dWt + 131072);          // 1280
    float* bias2   = bias1 + 1280;                    // 1280
    float* hWt     = bias2 + 1280;                    // 24576
    int* count     = (int*)(hWt + 24576);             // 1024
    int* list      = count + 1024;                    // 163840
    _Float16* bufBig = (_Float16*)(list + 163840);    // NA*512 (X1 / Xn / h)
    _Float16* bufY   = bufBig + (size_t)NA * 512;     // NA*256
    _Float16* bufP   = bufY + (size_t)NA * 256;       // NA*256
    // X1 lives in bufBig[0, NA*160); Xn in bufBig[NA*256, NA*512);
    // h (dense out) overwrites bufBig after Xn's last read — safe in-stream.
    _Float16* X1 = bufBig;
    _Float16* Xn = bufBig + (size_t)NA * 256;
    _Float16* h  = bufBig;

    zero_count_kernel<<<4, 256, 0, stream>>>(count);
    bucket_kernel<<<256, 256, 0, stream>>>(membership, count, list);
    cvt_w1_kernel<<<800, 256, 0, stream>>>(gc1W, gc1b, Wc1, bias1);
    cvt_w2_kernel<<<2560, 256, 0, stream>>>(gc2W, gc2b, Wc2, bias2);
    cvt_wd_kernel<<<512, 256, 0, stream>>>(dW, dWt);
    cvt_hw_kernel<<<96, 256, 0, stream>>>(hW, hWt);

    gather1_kernel<<<16384, 256, 0, stream>>>(af, a1, a2, a3, a4, X1);
    gemm_kernel<160, 256, 32, 0><<<1024, 256, 0, stream>>>(X1, nullptr, Wc1, bias1, bn1,
                                                           256 * 160, 256, bufY);
    pool_f16_kernel<<<16384, 256, 0, stream>>>(bufY, a1, a2, a3, a4, bufP);
    gather2n_kernel<<<16384, 256, 0, stream>>>(bufP, a1, a2, a3, a4, Xn);
    gemm_kernel<512, 256, 64, 1><<<1024, 256, 0, stream>>>(bufP, Xn, Wc2, bias2, bn2,
                                                           256 * 512, 256, bufY);
    pool_f16_kernel<<<16384, 256, 0, stream>>>(bufY, a1, a2, a3, a4, bufP);
    gemm_kernel<256, 512, 64, 0><<<2048, 256, 0, stream>>>(bufP, nullptr, dWt, db, bn3,
                                                           0, 0, h);
    seg_reduce_kernel<<<1024, 512, 0, stream>>>(h, count, list, fp);
    head_kernel<<<1024, 256, 0, stream>>>(fp, hWt, hb, logits, probs);
}

// Round 5
// 364.186 us; speedup vs baseline: 3.2063x; 1.0125x over previous
//
#include <hip/hip_runtime.h>
#include <hip/hip_bf16.h>
#include <math.h>

#define NA 65536
#define MAXSEG 160

typedef _Float16 half8 __attribute__((ext_vector_type(8)));
typedef _Float16 h4    __attribute__((ext_vector_type(4)));
typedef float float4v  __attribute__((ext_vector_type(4)));

// segment starts: 0, 4096, 16384, 36864, 57344 (all multiples of 128)
// All GEMM outputs are stored with a fixed per-128-col permutation:
//   position p = ((c&15)<<3) | (c>>4)   (c = true channel within 128-block)
//   inverse:  c = ((p&7)<<4) | (p>>3)
// Consumers: pool/gather2n are channel-agnostic; cvt_w2/cvt_wd permute W's
// k-dim to match; seg_reduce un-permutes when writing fp.

__device__ __forceinline__ int unperm128(int p) {
    return (p & ~127) + (((p & 127) & 7) << 4) + ((p & 127) >> 3);
}

__device__ __forceinline__ void atom_seg(int atom, int& d, int& loc,
                                         const int* a1, const int* a2,
                                         const int* a3, const int* a4,
                                         const int*& adj) {
    if (atom < 4096)       { d = 0; loc = 0; adj = nullptr; }
    else if (atom < 16384) { d = 1; adj = a1; loc = atom - 4096; }
    else if (atom < 36864) { d = 2; adj = a2; loc = atom - 16384; }
    else if (atom < 57344) { d = 3; adj = a3; loc = atom - 36864; }
    else                   { d = 4; adj = a4; loc = atom - 57344; }
}

__global__ void zero_count_kernel(int* __restrict__ count) {
    int i = blockIdx.x * 256 + threadIdx.x;
    if (i < 1024) count[i] = 0;
}

__global__ void bucket_kernel(const int* __restrict__ mem, int* __restrict__ count,
                              int* __restrict__ list) {
    int i = blockIdx.x * 256 + threadIdx.x;
    int seg = mem[i];
    int pos = atomicAdd(&count[seg], 1);
    if (pos < MAXSEG) list[seg * MAXSEG + pos] = i;
}

// ---- weight conversion -------------------------------------------------
// Wc1[seg][n][k] (5,256,160): k<75 self W, 75..149 neigh W, 150..159 zero
// (k-dim = raw atom features, no permutation)
__global__ void cvt_w1_kernel(const float* __restrict__ gc1W, const float* __restrict__ gc1b,
                              _Float16* __restrict__ Wc1, float* __restrict__ bias1) {
    int idx = blockIdx.x * 256 + threadIdx.x;       // 204800
    if (idx < 204800) {
        int k = idx % 160, n = (idx / 160) & 255, seg = idx / (160 * 256);
        float v = 0.f;
        if (k < 75) { int w = (seg == 0) ? 8 : (2 * seg - 1); v = gc1W[(w * 75 + k) * 256 + n]; }
        else if (k < 150 && seg > 0) { int w = 2 * (seg - 1); v = gc1W[(w * 75 + (k - 75)) * 256 + n]; }
        Wc1[(size_t)(seg * 256 + n) * 160 + k] = (_Float16)v;
    }
    if (idx < 1280) {
        int n = idx & 255, seg = idx >> 8;
        bias1[idx] = (seg == 0) ? gc1b[8 * 256 + n]
                                : gc1b[(2 * seg - 1) * 256 + n] + gc1b[2 * (seg - 1) * 256 + n];
    }
}

// Wc2[seg][n][k] (5,256,512): k<256 self (perm), 256..511 neigh (perm)
__global__ void cvt_w2_kernel(const float* __restrict__ gc2W, const float* __restrict__ gc2b,
                              _Float16* __restrict__ Wc2, float* __restrict__ bias2) {
    int idx = blockIdx.x * 256 + threadIdx.x;       // 655360
    if (idx < 655360) {
        int k = idx & 511, n = (idx >> 9) & 255, seg = idx >> 17;
        float v = 0.f;
        if (k < 256) {
            int w = (seg == 0) ? 8 : (2 * seg - 1);
            int chan = unperm128(k);
            v = gc2W[(w * 256 + chan) * 256 + n];
        } else if (seg > 0) {
            int w = 2 * (seg - 1);
            int chan = unperm128(k - 256);
            v = gc2W[(w * 256 + chan) * 256 + n];
        }
        Wc2[(size_t)(seg * 256 + n) * 512 + k] = (_Float16)v;
    }
    if (idx < 1280) {
        int n = idx & 255, seg = idx >> 8;
        bias2[idx] = (seg == 0) ? gc2b[8 * 256 + n]
                                : gc2b[(2 * seg - 1) * 256 + n] + gc2b[2 * (seg - 1) * 256 + n];
    }
}

// dWt[n][k] (512,256) = dW[unperm(k)][n]
__global__ void cvt_wd_kernel(const float* __restrict__ dW, _Float16* __restrict__ dWt) {
    int idx = blockIdx.x * 256 + threadIdx.x;       // 131072
    int n = idx >> 8, k = idx & 255;
    dWt[(size_t)n * 256 + k] = (_Float16)dW[(size_t)unperm128(k) * 512 + n];
}

// hWt[o][k] (24,1024) = hW[k][o]
__global__ void cvt_hw_kernel(const float* __restrict__ hW, float* __restrict__ hWt) {
    int idx = blockIdx.x * 256 + threadIdx.x;       // 24576
    int o = idx / 1024, k = idx & 1023;
    hWt[idx] = hW[k * 24 + o];
}

// ---- gathers -----------------------------------------------------------
// X1 (NA,160) f16 = [af(75) | sum-neigh af(75) | 0(10)]
__global__ __launch_bounds__(256) void gather1_kernel(
    const float* __restrict__ af,
    const int* __restrict__ a1, const int* __restrict__ a2,
    const int* __restrict__ a3, const int* __restrict__ a4,
    _Float16* __restrict__ X1) {
    int atom = blockIdx.x * 4 + (threadIdx.x >> 6);
    int lane = threadIdx.x & 63;
    int d, loc; const int* adj;
    atom_seg(atom, d, loc, a1, a2, a3, a4, adj);
    int nb[4];
    for (int j = 0; j < d; j++) nb[j] = adj[(size_t)loc * d + j];
    for (int k = lane; k < 75; k += 64) {
        X1[(size_t)atom * 160 + k] = (_Float16)af[(size_t)atom * 75 + k];
        float s = 0.f;
        for (int j = 0; j < d; j++) s += af[(size_t)nb[j] * 75 + k];
        X1[(size_t)atom * 160 + 75 + k] = (_Float16)s;
    }
    if (lane < 10) X1[(size_t)atom * 160 + 150 + lane] = (_Float16)0.f;
}

// Xn (NA,256) f16 = sum-neigh p (zeros for degree-0 atoms)
__global__ __launch_bounds__(256) void gather2n_kernel(
    const _Float16* __restrict__ p,
    const int* __restrict__ a1, const int* __restrict__ a2,
    const int* __restrict__ a3, const int* __restrict__ a4,
    _Float16* __restrict__ Xn) {
    int atom = blockIdx.x * 4 + (threadIdx.x >> 6);
    int lane = threadIdx.x & 63;
    int d, loc; const int* adj;
    atom_seg(atom, d, loc, a1, a2, a3, a4, adj);
    int nb[4];
    for (int j = 0; j < d; j++) nb[j] = adj[(size_t)loc * d + j];
    float s0 = 0.f, s1 = 0.f, s2 = 0.f, s3 = 0.f;
    for (int j = 0; j < d; j++) {
        h4 v = *(const h4*)(p + (size_t)nb[j] * 256 + lane * 4);
        s0 += (float)v[0]; s1 += (float)v[1]; s2 += (float)v[2]; s3 += (float)v[3];
    }
    h4 o; o[0] = (_Float16)s0; o[1] = (_Float16)s1; o[2] = (_Float16)s2; o[3] = (_Float16)s3;
    *(h4*)(Xn + (size_t)atom * 256 + lane * 4) = o;
}

// ---- MFMA GEMM: out = BN(relu(X @ Wt^T + bias)), permuted-col store ----
// Wave tile 32x128 (mi in 2, ni in 8); thread stores 8 same-row f16 as one
// dwordx4 at pos = 8*lrow + ni -> full-line writes, no partial-line amp.
// XOR-swizzled LDS, XCD-aware block swizzle, n-inner for A-panel L2 reuse.
template<int K, int N, int BK, int SPLIT>
__global__ __launch_bounds__(256) void gemm_kernel(
    const _Float16* __restrict__ X, const _Float16* __restrict__ Xn,
    const _Float16* __restrict__ Wt,
    const float* __restrict__ bias, const float* __restrict__ bnp,
    int wstride, int bstride, _Float16* __restrict__ out) {
    constexpr int NC8 = BK / 8;          // 16B chunks per row
    __shared__ _Float16 As[128 * BK];
    __shared__ _Float16 Bs[128 * BK];
    constexpr int nb = N / 128;
    int G = gridDim.x;
    int bid = (blockIdx.x & 7) * (G >> 3) + (blockIdx.x >> 3);  // XCD-aware
    int m0 = (bid / nb) * 128, n0 = (bid % nb) * 128;           // n-inner
    int t = m0 >> 7;
    int seg = (t < 32) ? 0 : (t < 128) ? 1 : (t < 288) ? 2 : (t < 448) ? 3 : 4;
    const _Float16* Wb = Wt + (size_t)seg * wstride;
    const float* bia = bias + seg * bstride;
    int tid = threadIdx.x, lane = tid & 63, wave = tid >> 6;
    int wm = wave * 32;
    int lrow = lane & 15, lq = lane >> 4;
    float4v acc[2][8] = {};
    for (int kc = 0; kc < K / BK; kc++) {
        #pragma unroll
        for (int p = tid; p < 128 * NC8; p += 256) {
            int row = p / NC8, c8 = p % NC8;
            int cs = c8 ^ (row & (NC8 - 1));
            const _Float16* srcA;
            if (!SPLIT) {
                srcA = X + (size_t)(m0 + row) * K + kc * BK + c8 * 8;
            } else {
                int kcol = kc * BK + c8 * 8;
                srcA = (kcol < 256) ? X  + (size_t)(m0 + row) * 256 + kcol
                                    : Xn + (size_t)(m0 + row) * 256 + (kcol - 256);
            }
            *(uint4*)(As + row * BK + cs * 8) = *(const uint4*)srcA;
            *(uint4*)(Bs + row * BK + cs * 8) =
                *(const uint4*)(Wb + (size_t)(n0 + row) * K + kc * BK + c8 * 8);
        }
        __syncthreads();
        #pragma unroll
        for (int kl = 0; kl < BK / 32; kl++) {
            half8 af[2], bf[8];
            #pragma unroll
            for (int i = 0; i < 2; i++) {
                int ra = wm + i * 16 + lrow;
                int ca = (kl * 4 + lq) ^ (ra & (NC8 - 1));
                af[i] = *(const half8*)(As + ra * BK + ca * 8);
            }
            #pragma unroll
            for (int j = 0; j < 8; j++) {
                int rb = j * 16 + lrow;
                int cb = (kl * 4 + lq) ^ (rb & (NC8 - 1));
                bf[j] = *(const half8*)(Bs + rb * BK + cb * 8);
            }
            #pragma unroll
            for (int mi = 0; mi < 2; mi++)
                #pragma unroll
                for (int ni = 0; ni < 8; ni++)
                    acc[mi][ni] = __builtin_amdgcn_mfma_f32_16x16x32_f16(af[mi], bf[ni], acc[mi][ni], 0, 0, 0);
        }
        __syncthreads();
    }
    // epilogue: per-channel params, then 8 dwordx4 stores (4 rows x 256B each)
    float bv[8], sc[8], mn[8], be[8];
    #pragma unroll
    for (int ni = 0; ni < 8; ni++) {
        int c = n0 + ni * 16 + lrow;               // true channel
        bv[ni] = bia[c];
        float g = bnp[c], vr = bnp[3 * N + c];
        mn[ni] = bnp[2 * N + c]; be[ni] = bnp[N + c];
        sc[ni] = g * rsqrtf(vr + 1e-3f);
    }
    #pragma unroll
    for (int mi = 0; mi < 2; mi++) {
        #pragma unroll
        for (int r = 0; r < 4; r++) {
            half8 pack;
            #pragma unroll
            for (int ni = 0; ni < 8; ni++) {
                float v = acc[mi][ni][r] + bv[ni];
                v = fmaxf(v, 0.f);
                v = sc[ni] * (v - mn[ni]) + be[ni];
                pack[ni] = (_Float16)v;
            }
            int row = m0 + wm + mi * 16 + lq * 4 + r;
            *(half8*)(out + (size_t)row * N + n0 + lrow * 8) = pack;
        }
    }
}

// ---- pool (f16): per atom elementwise max over {self, neighbors} -------
__global__ __launch_bounds__(256) void pool_f16_kernel(
    const _Float16* __restrict__ x,
    const int* __restrict__ a1, const int* __restrict__ a2,
    const int* __restrict__ a3, const int* __restrict__ a4,
    _Float16* __restrict__ out) {
    int atom = blockIdx.x * 4 + (threadIdx.x >> 6);
    int lane = threadIdx.x & 63;
    int d, loc; const int* adj;
    atom_seg(atom, d, loc, a1, a2, a3, a4, adj);
    h4 m = *(const h4*)(x + (size_t)atom * 256 + lane * 4);
    float m0 = (float)m[0], m1 = (float)m[1], m2 = (float)m[2], m3 = (float)m[3];
    for (int j = 0; j < d; j++) {
        int nb = adj[(size_t)loc * d + j];
        h4 v = *(const h4*)(x + (size_t)nb * 256 + lane * 4);
        m0 = fmaxf(m0, (float)v[0]); m1 = fmaxf(m1, (float)v[1]);
        m2 = fmaxf(m2, (float)v[2]); m3 = fmaxf(m3, (float)v[3]);
    }
    h4 o; o[0] = (_Float16)m0; o[1] = (_Float16)m1; o[2] = (_Float16)m2; o[3] = (_Float16)m3;
    *(h4*)(out + (size_t)atom * 256 + lane * 4) = o;
}

// ---- segment reduce: fp = tanh([seg_sum(h) | seg_max(h)]), un-permute --
__global__ __launch_bounds__(512) void seg_reduce_kernel(
    const _Float16* __restrict__ h, const int* __restrict__ count,
    const int* __restrict__ list, float* __restrict__ fp) {
    int seg = blockIdx.x, c = threadIdx.x;        // c = stored position
    int chan = unperm128(c);                      // true channel
    int n = count[seg]; if (n > MAXSEG) n = MAXSEG;
    float sum = 0.f, mx = -INFINITY;
    for (int a = 0; a < n; a++) {
        int row = list[seg * MAXSEG + a];
        float v = (float)h[(size_t)row * 512 + c];
        sum += v; mx = fmaxf(mx, v);
    }
    fp[(size_t)seg * 1024 + chan] = tanhf(sum);
    fp[(size_t)seg * 1024 + 512 + chan] = tanhf(mx);
}

// ---- head: all 256 threads active, k-split 8-way, hWt streamed ---------
__global__ __launch_bounds__(256) void head_kernel(
    const float* __restrict__ fp, const float* __restrict__ hWt,
    const float* __restrict__ hb, float* __restrict__ logits,
    float* __restrict__ probs) {
    __shared__ float fps[1024];
    __shared__ float red[32];
    int s = blockIdx.x;
    for (int i = threadIdx.x; i < 1024; i += 256) fps[i] = fp[(size_t)s * 1024 + i];
    __syncthreads();
    int t = threadIdx.x;
    int o = t >> 3, kp = t & 7;      // o 0..31 (24 active), kp 0..7
    float acc = 0.f;
    if (o < 24) {
        const float* w = hWt + (size_t)o * 1024 + kp * 128;
        const float* f = fps + kp * 128;
        #pragma unroll 8
        for (int i = 0; i < 128; i++) acc = fmaf(f[i], w[i], acc);
    }
    acc += __shfl_down(acc, 4, 64);
    acc += __shfl_down(acc, 2, 64);
    acc += __shfl_down(acc, 1, 64);
    if (o < 24 && kp == 0) red[o] = acc + hb[o];
    __syncthreads();
    if (t < 24) {
        float a = red[t];
        float an = red[t ^ 1];
        logits[(size_t)s * 24 + t] = a;
        probs[(size_t)s * 24 + t] = 1.f / (1.f + expf(an - a));
    }
}

extern "C" void kernel_launch(void* const* d_in, const int* in_sizes, int n_in,
                              void* d_out, int out_size, void* d_ws, size_t ws_size,
                              hipStream_t stream) {
    const float* af         = (const float*)d_in[0];
    const int*   membership = (const int*)d_in[2];
    const int*   a1 = (const int*)d_in[4];
    const int*   a2 = (const int*)d_in[5];
    const int*   a3 = (const int*)d_in[6];
    const int*   a4 = (const int*)d_in[7];
    const float* gc1W = (const float*)d_in[8];
    const float* gc1b = (const float*)d_in[9];
    const float* gc2W = (const float*)d_in[10];
    const float* gc2b = (const float*)d_in[11];
    const float* bn1  = (const float*)d_in[12];
    const float* bn2  = (const float*)d_in[13];
    const float* bn3  = (const float*)d_in[14];
    const float* dW   = (const float*)d_in[15];
    const float* db   = (const float*)d_in[16];
    const float* hW   = (const float*)d_in[17];
    const float* hb   = (const float*)d_in[18];

    float* out    = (float*)d_out;
    float* probs  = out;
    float* logits = out + 24576;
    float* fp     = out + 49152;

    _Float16* Wc1  = (_Float16*)d_ws;                 // 5*256*160 = 204800
    _Float16* Wc2  = Wc1 + 204800;                    // 5*256*512 = 655360
    _Float16* dWt  = Wc2 + 655360;                    // 512*256   = 131072
    float* bias1   = (float*)(dWt + 131072);          // 1280
    float* bias2   = bias1 + 1280;                    // 1280
    float* hWt     = bias2 + 1280;                    // 24576
    int* count     = (int*)(hWt + 24576);             // 1024
    int* list      = count + 1024;                    // 163840
    _Float16* bufBig = (_Float16*)(list + 163840);    // NA*512 (X1 / Xn / h)
    _Float16* bufY   = bufBig + (size_t)NA * 512;     // NA*256
    _Float16* bufP   = bufY + (size_t)NA * 256;       // NA*256
    _Float16* X1 = bufBig;
    _Float16* Xn = bufBig + (size_t)NA * 256;
    _Float16* h  = bufBig;

    zero_count_kernel<<<4, 256, 0, stream>>>(count);
    bucket_kernel<<<256, 256, 0, stream>>>(membership, count, list);
    cvt_w1_kernel<<<800, 256, 0, stream>>>(gc1W, gc1b, Wc1, bias1);
    cvt_w2_kernel<<<2560, 256, 0, stream>>>(gc2W, gc2b, Wc2, bias2);
    cvt_wd_kernel<<<512, 256, 0, stream>>>(dW, dWt);
    cvt_hw_kernel<<<96, 256, 0, stream>>>(hW, hWt);

    gather1_kernel<<<16384, 256, 0, stream>>>(af, a1, a2, a3, a4, X1);
    gemm_kernel<160, 256, 32, 0><<<1024, 256, 0, stream>>>(X1, nullptr, Wc1, bias1, bn1,
                                                           256 * 160, 256, bufY);
    pool_f16_kernel<<<16384, 256, 0, stream>>>(bufY, a1, a2, a3, a4, bufP);
    gather2n_kernel<<<16384, 256, 0, stream>>>(bufP, a1, a2, a3, a4, Xn);
    gemm_kernel<512, 256, 64, 1><<<1024, 256, 0, stream>>>(bufP, Xn, Wc2, bias2, bn2,
                                                           256 * 512, 256, bufY);
    pool_f16_kernel<<<16384, 256, 0, stream>>>(bufY, a1, a2, a3, a4, bufP);
    gemm_kernel<256, 512, 64, 0><<<2048, 256, 0, stream>>>(bufP, nullptr, dWt, db, bn3,
                                                           0, 0, h);
    seg_reduce_kernel<<<1024, 512, 0, stream>>>(h, count, list, fp);
    head_kernel<<<1024, 256, 0, stream>>>(fp, hWt, hb, logits, probs);
}

// Round 6
// 348.285 us; speedup vs baseline: 3.3527x; 1.0457x over previous
//
#include <hip/hip_runtime.h>
#include <hip/hip_bf16.h>
#include <math.h>

#define NA 65536
#define MAXSEG 160

typedef _Float16 half8 __attribute__((ext_vector_type(8)));
typedef _Float16 h4    __attribute__((ext_vector_type(4)));
typedef float float4v  __attribute__((ext_vector_type(4)));

typedef __attribute__((address_space(3))) unsigned int lds_uint;
typedef __attribute__((address_space(1))) const unsigned int g_uint;

// async 16B global->LDS (one instr per wave: lane i's 16B lands at l + i*16)
__device__ __forceinline__ void async16(const void* g, void* l) {
    __builtin_amdgcn_global_load_lds((g_uint*)g, (lds_uint*)l, 16, 0, 0);
}

// segment starts: 0, 4096, 16384, 36864, 57344 (all multiples of 128)
// All GEMM outputs are stored with a fixed per-128-col permutation:
//   position p = ((c&15)<<3) | (c>>4)   (c = true channel within 128-block)
//   inverse:  c = ((p&7)<<4) | (p>>3)
// Consumers: pool/gather2n are channel-agnostic; cvt_w2/cvt_wd permute W's
// k-dim to match; seg_reduce un-permutes when writing fp.

__device__ __forceinline__ int unperm128(int p) {
    return (p & ~127) + (((p & 127) & 7) << 4) + ((p & 127) >> 3);
}

__device__ __forceinline__ void atom_seg(int atom, int& d, int& loc,
                                         const int* a1, const int* a2,
                                         const int* a3, const int* a4,
                                         const int*& adj) {
    if (atom < 4096)       { d = 0; loc = 0; adj = nullptr; }
    else if (atom < 16384) { d = 1; adj = a1; loc = atom - 4096; }
    else if (atom < 36864) { d = 2; adj = a2; loc = atom - 16384; }
    else if (atom < 57344) { d = 3; adj = a3; loc = atom - 36864; }
    else                   { d = 4; adj = a4; loc = atom - 57344; }
}

__global__ void zero_count_kernel(int* __restrict__ count) {
    int i = blockIdx.x * 256 + threadIdx.x;
    if (i < 1024) count[i] = 0;
}

__global__ void bucket_kernel(const int* __restrict__ mem, int* __restrict__ count,
                              int* __restrict__ list) {
    int i = blockIdx.x * 256 + threadIdx.x;
    int seg = mem[i];
    int pos = atomicAdd(&count[seg], 1);
    if (pos < MAXSEG) list[seg * MAXSEG + pos] = i;
}

// ---- weight conversion -------------------------------------------------
__global__ void cvt_w1_kernel(const float* __restrict__ gc1W, const float* __restrict__ gc1b,
                              _Float16* __restrict__ Wc1, float* __restrict__ bias1) {
    int idx = blockIdx.x * 256 + threadIdx.x;       // 204800
    if (idx < 204800) {
        int k = idx % 160, n = (idx / 160) & 255, seg = idx / (160 * 256);
        float v = 0.f;
        if (k < 75) { int w = (seg == 0) ? 8 : (2 * seg - 1); v = gc1W[(w * 75 + k) * 256 + n]; }
        else if (k < 150 && seg > 0) { int w = 2 * (seg - 1); v = gc1W[(w * 75 + (k - 75)) * 256 + n]; }
        Wc1[(size_t)(seg * 256 + n) * 160 + k] = (_Float16)v;
    }
    if (idx < 1280) {
        int n = idx & 255, seg = idx >> 8;
        bias1[idx] = (seg == 0) ? gc1b[8 * 256 + n]
                                : gc1b[(2 * seg - 1) * 256 + n] + gc1b[2 * (seg - 1) * 256 + n];
    }
}

__global__ void cvt_w2_kernel(const float* __restrict__ gc2W, const float* __restrict__ gc2b,
                              _Float16* __restrict__ Wc2, float* __restrict__ bias2) {
    int idx = blockIdx.x * 256 + threadIdx.x;       // 655360
    if (idx < 655360) {
        int k = idx & 511, n = (idx >> 9) & 255, seg = idx >> 17;
        float v = 0.f;
        if (k < 256) {
            int w = (seg == 0) ? 8 : (2 * seg - 1);
            v = gc2W[(w * 256 + unperm128(k)) * 256 + n];
        } else if (seg > 0) {
            int w = 2 * (seg - 1);
            v = gc2W[(w * 256 + unperm128(k - 256)) * 256 + n];
        }
        Wc2[(size_t)(seg * 256 + n) * 512 + k] = (_Float16)v;
    }
    if (idx < 1280) {
        int n = idx & 255, seg = idx >> 8;
        bias2[idx] = (seg == 0) ? gc2b[8 * 256 + n]
                                : gc2b[(2 * seg - 1) * 256 + n] + gc2b[2 * (seg - 1) * 256 + n];
    }
}

__global__ void cvt_wd_kernel(const float* __restrict__ dW, _Float16* __restrict__ dWt) {
    int idx = blockIdx.x * 256 + threadIdx.x;       // 131072
    int n = idx >> 8, k = idx & 255;
    dWt[(size_t)n * 256 + k] = (_Float16)dW[(size_t)unperm128(k) * 512 + n];
}

__global__ void cvt_hw_kernel(const float* __restrict__ hW, float* __restrict__ hWt) {
    int idx = blockIdx.x * 256 + threadIdx.x;       // 24576
    int o = idx / 1024, k = idx & 1023;
    hWt[idx] = hW[k * 24 + o];
}

// ---- gathers -----------------------------------------------------------
__global__ __launch_bounds__(256) void gather1_kernel(
    const float* __restrict__ af,
    const int* __restrict__ a1, const int* __restrict__ a2,
    const int* __restrict__ a3, const int* __restrict__ a4,
    _Float16* __restrict__ X1) {
    int atom = blockIdx.x * 4 + (threadIdx.x >> 6);
    int lane = threadIdx.x & 63;
    int d, loc; const int* adj;
    atom_seg(atom, d, loc, a1, a2, a3, a4, adj);
    int nb[4];
    for (int j = 0; j < d; j++) nb[j] = adj[(size_t)loc * d + j];
    for (int k = lane; k < 75; k += 64) {
        X1[(size_t)atom * 160 + k] = (_Float16)af[(size_t)atom * 75 + k];
        float s = 0.f;
        for (int j = 0; j < d; j++) s += af[(size_t)nb[j] * 75 + k];
        X1[(size_t)atom * 160 + 75 + k] = (_Float16)s;
    }
    if (lane < 10) X1[(size_t)atom * 160 + 150 + lane] = (_Float16)0.f;
}

__global__ __launch_bounds__(256) void gather2n_kernel(
    const _Float16* __restrict__ p,
    const int* __restrict__ a1, const int* __restrict__ a2,
    const int* __restrict__ a3, const int* __restrict__ a4,
    _Float16* __restrict__ Xn) {
    int atom = blockIdx.x * 4 + (threadIdx.x >> 6);
    int lane = threadIdx.x & 63;
    int d, loc; const int* adj;
    atom_seg(atom, d, loc, a1, a2, a3, a4, adj);
    int nb[4];
    for (int j = 0; j < d; j++) nb[j] = adj[(size_t)loc * d + j];
    float s0 = 0.f, s1 = 0.f, s2 = 0.f, s3 = 0.f;
    for (int j = 0; j < d; j++) {
        h4 v = *(const h4*)(p + (size_t)nb[j] * 256 + lane * 4);
        s0 += (float)v[0]; s1 += (float)v[1]; s2 += (float)v[2]; s3 += (float)v[3];
    }
    h4 o; o[0] = (_Float16)s0; o[1] = (_Float16)s1; o[2] = (_Float16)s2; o[3] = (_Float16)s3;
    *(h4*)(Xn + (size_t)atom * 256 + lane * 4) = o;
}

// ---- MFMA GEMM, m97-style: 128x128 block, 4 waves x (64x64), async stage
// global_load_lds 16B with the XOR swizzle folded into the per-lane global
// gather address; conflict-free b128 frag reads; permuted-col store.
template<int K, int N, int BK, int SPLIT>
__global__ __launch_bounds__(256) void gemm_kernel(
    const _Float16* __restrict__ X, const _Float16* __restrict__ Xn,
    const _Float16* __restrict__ Wt,
    const float* __restrict__ bias, const float* __restrict__ bnp,
    int wstride, int bstride, _Float16* __restrict__ out) {
    constexpr int NC8 = BK / 8;                  // 16B chunks per row
    constexpr int MASK = NC8 - 1;
    __shared__ __align__(16) _Float16 As[128 * BK];
    __shared__ __align__(16) _Float16 Bs[128 * BK];
    constexpr int nb = N / 128;
    int G = gridDim.x;
    int bid = (blockIdx.x & 7) * (G >> 3) + (blockIdx.x >> 3);  // XCD-aware
    int m0 = (bid / nb) * 128, n0 = (bid % nb) * 128;           // n-inner
    int t = m0 >> 7;
    int seg = (t < 32) ? 0 : (t < 128) ? 1 : (t < 288) ? 2 : (t < 448) ? 3 : 4;
    const _Float16* Wb = Wt + (size_t)seg * wstride;
    const float* bia = bias + seg * bstride;
    int tid = threadIdx.x, lane = tid & 63, wave = tid >> 6;
    int wm = (wave >> 1) * 64, wn = (wave & 1) * 64;
    int lrow = lane & 15, lq = lane >> 4;
    float4v acc[4][4] = {};
    for (int kc = 0; kc < K / BK; kc++) {
        // async stage: slot s = row*NC8 + cs lands at LDS addr s*16;
        // lane L of wave w in round q owns slot q*256 + w*64 + L.
        #pragma unroll
        for (int q = 0; q < NC8 / 2; q++) {
            int slot = q * 256 + wave * 64 + lane;
            int row = slot / NC8;
            int cs = slot & MASK;
            int c8 = cs ^ (row & MASK);
            const _Float16* gA;
            if (!SPLIT) {
                gA = X + (size_t)(m0 + row) * K + kc * BK + c8 * 8;
            } else {
                int kcol = kc * BK + c8 * 8;
                gA = (kcol < 256) ? X  + (size_t)(m0 + row) * 256 + kcol
                                  : Xn + (size_t)(m0 + row) * 256 + (kcol - 256);
            }
            async16(gA, As + (size_t)(q * 256 + wave * 64) * 8);
            const _Float16* gB = Wb + (size_t)(n0 + row) * K + kc * BK + c8 * 8;
            async16(gB, Bs + (size_t)(q * 256 + wave * 64) * 8);
        }
        __syncthreads();
        #pragma unroll
        for (int kl = 0; kl < BK / 32; kl++) {
            half8 af[4], bf[4];
            #pragma unroll
            for (int i = 0; i < 4; i++) {
                int ra = wm + i * 16 + lrow;
                int ca = (kl * 4 + lq) ^ (ra & MASK);
                af[i] = *(const half8*)(As + ra * BK + ca * 8);
                int rb = wn + i * 16 + lrow;
                int cb = (kl * 4 + lq) ^ (rb & MASK);
                bf[i] = *(const half8*)(Bs + rb * BK + cb * 8);
            }
            #pragma unroll
            for (int mi = 0; mi < 4; mi++)
                #pragma unroll
                for (int ni = 0; ni < 4; ni++)
                    acc[mi][ni] = __builtin_amdgcn_mfma_f32_16x16x32_f16(af[mi], bf[ni], acc[mi][ni], 0, 0, 0);
        }
        __syncthreads();
    }
    // epilogue: permuted-col store. True col c = n0+wn+ni*16+lrow maps to
    // position p = lrow*8 + (wave&1)*4 + ni  -> 4 contiguous halves/thread.
    float bv[4], sc[4], mn[4], be[4];
    #pragma unroll
    for (int ni = 0; ni < 4; ni++) {
        int c = n0 + wn + ni * 16 + lrow;
        bv[ni] = bia[c];
        float g = bnp[c], vr = bnp[3 * N + c];
        mn[ni] = bnp[2 * N + c]; be[ni] = bnp[N + c];
        sc[ni] = g * rsqrtf(vr + 1e-3f);
    }
    int p0 = n0 + lrow * 8 + (wave & 1) * 4;
    #pragma unroll
    for (int mi = 0; mi < 4; mi++) {
        #pragma unroll
        for (int r = 0; r < 4; r++) {
            h4 pack;
            #pragma unroll
            for (int ni = 0; ni < 4; ni++) {
                float v = acc[mi][ni][r] + bv[ni];
                v = fmaxf(v, 0.f);
                v = sc[ni] * (v - mn[ni]) + be[ni];
                pack[ni] = (_Float16)v;
            }
            int row = m0 + wm + mi * 16 + lq * 4 + r;
            *(h4*)(out + (size_t)row * N + p0) = pack;
        }
    }
}

// ---- pool (f16) --------------------------------------------------------
__global__ __launch_bounds__(256) void pool_f16_kernel(
    const _Float16* __restrict__ x,
    const int* __restrict__ a1, const int* __restrict__ a2,
    const int* __restrict__ a3, const int* __restrict__ a4,
    _Float16* __restrict__ out) {
    int atom = blockIdx.x * 4 + (threadIdx.x >> 6);
    int lane = threadIdx.x & 63;
    int d, loc; const int* adj;
    atom_seg(atom, d, loc, a1, a2, a3, a4, adj);
    h4 m = *(const h4*)(x + (size_t)atom * 256 + lane * 4);
    float m0 = (float)m[0], m1 = (float)m[1], m2 = (float)m[2], m3 = (float)m[3];
    for (int j = 0; j < d; j++) {
        int nb = adj[(size_t)loc * d + j];
        h4 v = *(const h4*)(x + (size_t)nb * 256 + lane * 4);
        m0 = fmaxf(m0, (float)v[0]); m1 = fmaxf(m1, (float)v[1]);
        m2 = fmaxf(m2, (float)v[2]); m3 = fmaxf(m3, (float)v[3]);
    }
    h4 o; o[0] = (_Float16)m0; o[1] = (_Float16)m1; o[2] = (_Float16)m2; o[3] = (_Float16)m3;
    *(h4*)(out + (size_t)atom * 256 + lane * 4) = o;
}

// ---- segment reduce (un-permutes) --------------------------------------
__global__ __launch_bounds__(512) void seg_reduce_kernel(
    const _Float16* __restrict__ h, const int* __restrict__ count,
    const int* __restrict__ list, float* __restrict__ fp) {
    int seg = blockIdx.x, c = threadIdx.x;        // c = stored position
    int chan = unperm128(c);                      // true channel
    int n = count[seg]; if (n > MAXSEG) n = MAXSEG;
    float sum = 0.f, mx = -INFINITY;
    for (int a = 0; a < n; a++) {
        int row = list[seg * MAXSEG + a];
        float v = (float)h[(size_t)row * 512 + c];
        sum += v; mx = fmaxf(mx, v);
    }
    fp[(size_t)seg * 1024 + chan] = tanhf(sum);
    fp[(size_t)seg * 1024 + 512 + chan] = tanhf(mx);
}

// ---- head --------------------------------------------------------------
__global__ __launch_bounds__(256) void head_kernel(
    const float* __restrict__ fp, const float* __restrict__ hWt,
    const float* __restrict__ hb, float* __restrict__ logits,
    float* __restrict__ probs) {
    __shared__ float fps[1024];
    __shared__ float red[32];
    int s = blockIdx.x;
    for (int i = threadIdx.x; i < 1024; i += 256) fps[i] = fp[(size_t)s * 1024 + i];
    __syncthreads();
    int t = threadIdx.x;
    int o = t >> 3, kp = t & 7;
    float acc = 0.f;
    if (o < 24) {
        const float* w = hWt + (size_t)o * 1024 + kp * 128;
        const float* f = fps + kp * 128;
        #pragma unroll 8
        for (int i = 0; i < 128; i++) acc = fmaf(f[i], w[i], acc);
    }
    acc += __shfl_down(acc, 4, 64);
    acc += __shfl_down(acc, 2, 64);
    acc += __shfl_down(acc, 1, 64);
    if (o < 24 && kp == 0) red[o] = acc + hb[o];
    __syncthreads();
    if (t < 24) {
        float a = red[t];
        float an = red[t ^ 1];
        logits[(size_t)s * 24 + t] = a;
        probs[(size_t)s * 24 + t] = 1.f / (1.f + expf(an - a));
    }
}

extern "C" void kernel_launch(void* const* d_in, const int* in_sizes, int n_in,
                              void* d_out, int out_size, void* d_ws, size_t ws_size,
                              hipStream_t stream) {
    const float* af         = (const float*)d_in[0];
    const int*   membership = (const int*)d_in[2];
    const int*   a1 = (const int*)d_in[4];
    const int*   a2 = (const int*)d_in[5];
    const int*   a3 = (const int*)d_in[6];
    const int*   a4 = (const int*)d_in[7];
    const float* gc1W = (const float*)d_in[8];
    const float* gc1b = (const float*)d_in[9];
    const float* gc2W = (const float*)d_in[10];
    const float* gc2b = (const float*)d_in[11];
    const float* bn1  = (const float*)d_in[12];
    const float* bn2  = (const float*)d_in[13];
    const float* bn3  = (const float*)d_in[14];
    const float* dW   = (const float*)d_in[15];
    const float* db   = (const float*)d_in[16];
    const float* hW   = (const float*)d_in[17];
    const float* hb   = (const float*)d_in[18];

    float* out    = (float*)d_out;
    float* probs  = out;
    float* logits = out + 24576;
    float* fp     = out + 49152;

    _Float16* Wc1  = (_Float16*)d_ws;                 // 5*256*160 = 204800
    _Float16* Wc2  = Wc1 + 204800;                    // 5*256*512 = 655360
    _Float16* dWt  = Wc2 + 655360;                    // 512*256   = 131072
    float* bias1   = (float*)(dWt + 131072);          // 1280
    float* bias2   = bias1 + 1280;                    // 1280
    float* hWt     = bias2 + 1280;                    // 24576
    int* count     = (int*)(hWt + 24576);             // 1024
    int* list      = count + 1024;                    // 163840
    _Float16* bufBig = (_Float16*)(list + 163840);    // NA*512 (X1 / Xn / h)
    _Float16* bufY   = bufBig + (size_t)NA * 512;     // NA*256
    _Float16* bufP   = bufY + (size_t)NA * 256;       // NA*256
    _Float16* X1 = bufBig;
    _Float16* Xn = bufBig + (size_t)NA * 256;
    _Float16* h  = bufBig;

    zero_count_kernel<<<4, 256, 0, stream>>>(count);
    bucket_kernel<<<256, 256, 0, stream>>>(membership, count, list);
    cvt_w1_kernel<<<800, 256, 0, stream>>>(gc1W, gc1b, Wc1, bias1);
    cvt_w2_kernel<<<2560, 256, 0, stream>>>(gc2W, gc2b, Wc2, bias2);
    cvt_wd_kernel<<<512, 256, 0, stream>>>(dW, dWt);
    cvt_hw_kernel<<<96, 256, 0, stream>>>(hW, hWt);

    gather1_kernel<<<16384, 256, 0, stream>>>(af, a1, a2, a3, a4, X1);
    gemm_kernel<160, 256, 32, 0><<<1024, 256, 0, stream>>>(X1, nullptr, Wc1, bias1, bn1,
                                                           256 * 160, 256, bufY);
    pool_f16_kernel<<<16384, 256, 0, stream>>>(bufY, a1, a2, a3, a4, bufP);
    gather2n_kernel<<<16384, 256, 0, stream>>>(bufP, a1, a2, a3, a4, Xn);
    gemm_kernel<512, 256, 64, 1><<<1024, 256, 0, stream>>>(bufP, Xn, Wc2, bias2, bn2,
                                                           256 * 512, 256, bufY);
    pool_f16_kernel<<<16384, 256, 0, stream>>>(bufY, a1, a2, a3, a4, bufP);
    gemm_kernel<256, 512, 64, 0><<<2048, 256, 0, stream>>>(bufP, nullptr, dWt, db, bn3,
                                                           0, 0, h);
    seg_reduce_kernel<<<1024, 512, 0, stream>>>(h, count, list, fp);
    head_kernel<<<1024, 256, 0, stream>>>(fp, hWt, hb, logits, probs);
}

// Round 7
// 311.821 us; speedup vs baseline: 3.7447x; 1.1169x over previous
//
#include <hip/hip_runtime.h>
#include <hip/hip_bf16.h>
#include <math.h>

#define NA 65536
#define MAXSEG 160

typedef _Float16 half8 __attribute__((ext_vector_type(8)));
typedef _Float16 h4    __attribute__((ext_vector_type(4)));
typedef float float4v  __attribute__((ext_vector_type(4)));

typedef __attribute__((address_space(3))) unsigned int lds_uint;
typedef __attribute__((address_space(1))) const unsigned int g_uint;

// async 16B global->LDS (one instr per wave: lane i's 16B lands at l + i*16)
__device__ __forceinline__ void async16(const void* g, void* l) {
    __builtin_amdgcn_global_load_lds((g_uint*)g, (lds_uint*)l, 16, 0, 0);
}

// segment starts: 0, 4096, 16384, 36864, 57344 (all multiples of 128)
// All GEMM outputs are stored with a fixed per-128-col permutation:
//   position p = ((c&15)<<3) | (c>>4); inverse c = ((p&7)<<4) | (p>>3)
// pool/gather2n are channel-agnostic; prep permutes W2/dW k-dims to match;
// seg_reduce un-permutes when writing fp.

__device__ __forceinline__ int unperm128(int p) {
    return (p & ~127) + (((p & 127) & 7) << 4) + ((p & 127) >> 3);
}

__device__ __forceinline__ void atom_seg(int atom, int& d, int& loc,
                                         const int* a1, const int* a2,
                                         const int* a3, const int* a4,
                                         const int*& adj) {
    if (atom < 4096)       { d = 0; loc = 0; adj = nullptr; }
    else if (atom < 16384) { d = 1; adj = a1; loc = atom - 4096; }
    else if (atom < 36864) { d = 2; adj = a2; loc = atom - 16384; }
    else if (atom < 57344) { d = 3; adj = a3; loc = atom - 36864; }
    else                   { d = 4; adj = a4; loc = atom - 57344; }
}

// ---- one prep kernel: af->f16(pad 80), W1/W2/dW/hW conversion, zero ----
// block ranges: [0,5120) af16 | [5120,5920) W1 | [5920,8480) W2
//               [8480,8992) dWt | [8992,9088) hWt | [9088,9092) zero
__global__ __launch_bounds__(256) void prep_kernel(
    const float* __restrict__ af,
    const float* __restrict__ gc1W, const float* __restrict__ gc1b,
    const float* __restrict__ gc2W, const float* __restrict__ gc2b,
    const float* __restrict__ dW, const float* __restrict__ hW,
    _Float16* __restrict__ af16, _Float16* __restrict__ Wc1, float* __restrict__ bias1,
    _Float16* __restrict__ Wc2, float* __restrict__ bias2,
    _Float16* __restrict__ dWt, float* __restrict__ hWt, int* __restrict__ count) {
    int b = blockIdx.x, t = threadIdx.x;
    if (b < 5120) {                       // af16: NA*20 threads, h4 each
        int idx = b * 256 + t;
        int atom = idx / 20, k4 = idx - atom * 20;
        int c0 = k4 * 4;
        h4 o;
        #pragma unroll
        for (int j = 0; j < 4; j++) {
            int c = c0 + j;
            o[j] = (_Float16)((c < 75) ? af[(size_t)atom * 75 + c] : 0.f);
        }
        *(h4*)(af16 + (size_t)atom * 80 + c0) = o;
    } else if (b < 5920) {                // Wc1: k<80 self(75+5z), 80..159 neigh
        int idx = (b - 5120) * 256 + t;
        if (idx < 204800) {
            int k = idx % 160, n = (idx / 160) & 255, seg = idx / (160 * 256);
            float v = 0.f;
            if (k < 80) {
                if (k < 75) { int w = (seg == 0) ? 8 : (2 * seg - 1); v = gc1W[(w * 75 + k) * 256 + n]; }
            } else {
                int kk = k - 80;
                if (kk < 75 && seg > 0) { int w = 2 * (seg - 1); v = gc1W[(w * 75 + kk) * 256 + n]; }
            }
            Wc1[(size_t)(seg * 256 + n) * 160 + k] = (_Float16)v;
        }
        if (idx < 1280) {
            int n = idx & 255, seg = idx >> 8;
            bias1[idx] = (seg == 0) ? gc1b[8 * 256 + n]
                                    : gc1b[(2 * seg - 1) * 256 + n] + gc1b[2 * (seg - 1) * 256 + n];
        }
    } else if (b < 8480) {                // Wc2 (perm k)
        int idx = (b - 5920) * 256 + t;
        int k = idx & 511, n = (idx >> 9) & 255, seg = idx >> 17;
        float v = 0.f;
        if (k < 256) {
            int w = (seg == 0) ? 8 : (2 * seg - 1);
            v = gc2W[(w * 256 + unperm128(k)) * 256 + n];
        } else if (seg > 0) {
            int w = 2 * (seg - 1);
            v = gc2W[(w * 256 + unperm128(k - 256)) * 256 + n];
        }
        Wc2[(size_t)(seg * 256 + n) * 512 + k] = (_Float16)v;
        if (idx < 1280) {
            int nn = idx & 255, sg = idx >> 8;
            bias2[idx] = (sg == 0) ? gc2b[8 * 256 + nn]
                                   : gc2b[(2 * sg - 1) * 256 + nn] + gc2b[2 * (sg - 1) * 256 + nn];
        }
    } else if (b < 8992) {                // dWt (perm k)
        int idx = (b - 8480) * 256 + t;
        int n = idx >> 8, k = idx & 255;
        dWt[(size_t)n * 256 + k] = (_Float16)dW[(size_t)unperm128(k) * 512 + n];
    } else if (b < 9088) {                // hWt
        int idx = (b - 8992) * 256 + t;
        int o = idx / 1024, k = idx & 1023;
        hWt[idx] = hW[k * 24 + o];
    } else {                              // zero counts
        int i = (b - 9088) * 256 + t;
        if (i < 1024) count[i] = 0;
    }
}

__global__ void bucket_kernel(const int* __restrict__ mem, int* __restrict__ count,
                              int* __restrict__ list) {
    int i = blockIdx.x * 256 + threadIdx.x;
    int seg = mem[i];
    int pos = atomicAdd(&count[seg], 1);
    if (pos < MAXSEG) list[seg * MAXSEG + pos] = i;
}

// ---- gather1n: Xn1 (NA,80) f16 = sum-neigh af16 (zeros for deg0/pad) ---
__global__ __launch_bounds__(256) void gather1n_kernel(
    const _Float16* __restrict__ af16,
    const int* __restrict__ a1, const int* __restrict__ a2,
    const int* __restrict__ a3, const int* __restrict__ a4,
    _Float16* __restrict__ Xn1) {
    int idx = blockIdx.x * 256 + threadIdx.x;     // NA*20
    int atom = idx / 20, k4 = idx - atom * 20;
    int c0 = k4 * 4;
    int d, loc; const int* adj;
    atom_seg(atom, d, loc, a1, a2, a3, a4, adj);
    float s0 = 0.f, s1 = 0.f, s2 = 0.f, s3 = 0.f;
    for (int j = 0; j < d; j++) {
        int nb = adj[(size_t)loc * d + j];
        h4 v = *(const h4*)(af16 + (size_t)nb * 80 + c0);
        s0 += (float)v[0]; s1 += (float)v[1]; s2 += (float)v[2]; s3 += (float)v[3];
    }
    h4 o; o[0] = (_Float16)s0; o[1] = (_Float16)s1; o[2] = (_Float16)s2; o[3] = (_Float16)s3;
    *(h4*)(Xn1 + (size_t)atom * 80 + c0) = o;
}

// ---- gather2n: Xn (NA,256) f16 = sum-neigh p; 16B/lane, 8 atoms/block --
__global__ __launch_bounds__(256) void gather2n_kernel(
    const _Float16* __restrict__ p,
    const int* __restrict__ a1, const int* __restrict__ a2,
    const int* __restrict__ a3, const int* __restrict__ a4,
    _Float16* __restrict__ Xn) {
    int atom = blockIdx.x * 8 + (threadIdx.x >> 5);
    int l = threadIdx.x & 31;
    int d, loc; const int* adj;
    atom_seg(atom, d, loc, a1, a2, a3, a4, adj);
    float s[8] = {};
    for (int j = 0; j < d; j++) {
        int nb = adj[(size_t)loc * d + j];
        half8 v = *(const half8*)(p + (size_t)nb * 256 + l * 8);
        #pragma unroll
        for (int e = 0; e < 8; e++) s[e] += (float)v[e];
    }
    half8 o;
    #pragma unroll
    for (int e = 0; e < 8; e++) o[e] = (_Float16)s[e];
    *(half8*)(Xn + (size_t)atom * 256 + l * 8) = o;
}

// ---- MFMA GEMM, m97-style: 128x128 block, 4 waves x (64x64), async stage
// SB=0: A from X (stride K). SB>0: A cols [0,SB) from X, [SB,K) from Xn,
// both with row stride SB (K = 2*SB).
template<int K, int N, int BK, int SB>
__global__ __launch_bounds__(256) void gemm_kernel(
    const _Float16* __restrict__ X, const _Float16* __restrict__ Xn,
    const _Float16* __restrict__ Wt,
    const float* __restrict__ bias, const float* __restrict__ bnp,
    int wstride, int bstride, _Float16* __restrict__ out) {
    constexpr int NC8 = BK / 8;                  // 16B chunks per row
    constexpr int MASK = NC8 - 1;
    __shared__ __align__(16) _Float16 As[128 * BK];
    __shared__ __align__(16) _Float16 Bs[128 * BK];
    constexpr int nb = N / 128;
    int G = gridDim.x;
    int bid = (blockIdx.x & 7) * (G >> 3) + (blockIdx.x >> 3);  // XCD-aware
    int m0 = (bid / nb) * 128, n0 = (bid % nb) * 128;           // n-inner
    int t = m0 >> 7;
    int seg = (t < 32) ? 0 : (t < 128) ? 1 : (t < 288) ? 2 : (t < 448) ? 3 : 4;
    const _Float16* Wb = Wt + (size_t)seg * wstride;
    const float* bia = bias + seg * bstride;
    int tid = threadIdx.x, lane = tid & 63, wave = tid >> 6;
    int wm = (wave >> 1) * 64, wn = (wave & 1) * 64;
    int lrow = lane & 15, lq = lane >> 4;
    float4v acc[4][4] = {};
    for (int kc = 0; kc < K / BK; kc++) {
        #pragma unroll
        for (int q = 0; q < NC8 / 2; q++) {
            int slot = q * 256 + wave * 64 + lane;
            int row = slot / NC8;
            int cs = slot & MASK;
            int c8 = cs ^ (row & MASK);
            const _Float16* gA;
            if (SB == 0) {
                gA = X + (size_t)(m0 + row) * K + kc * BK + c8 * 8;
            } else {
                int kcol = kc * BK + c8 * 8;
                gA = (kcol < SB) ? X  + (size_t)(m0 + row) * SB + kcol
                                 : Xn + (size_t)(m0 + row) * SB + (kcol - SB);
            }
            async16(gA, As + (size_t)(q * 256 + wave * 64) * 8);
            const _Float16* gB = Wb + (size_t)(n0 + row) * K + kc * BK + c8 * 8;
            async16(gB, Bs + (size_t)(q * 256 + wave * 64) * 8);
        }
        __syncthreads();
        #pragma unroll
        for (int kl = 0; kl < BK / 32; kl++) {
            half8 af[4], bf[4];
            #pragma unroll
            for (int i = 0; i < 4; i++) {
                int ra = wm + i * 16 + lrow;
                int ca = (kl * 4 + lq) ^ (ra & MASK);
                af[i] = *(const half8*)(As + ra * BK + ca * 8);
                int rb = wn + i * 16 + lrow;
                int cb = (kl * 4 + lq) ^ (rb & MASK);
                bf[i] = *(const half8*)(Bs + rb * BK + cb * 8);
            }
            #pragma unroll
            for (int mi = 0; mi < 4; mi++)
                #pragma unroll
                for (int ni = 0; ni < 4; ni++)
                    acc[mi][ni] = __builtin_amdgcn_mfma_f32_16x16x32_f16(af[mi], bf[ni], acc[mi][ni], 0, 0, 0);
        }
        __syncthreads();
    }
    float bv[4], sc[4], mn[4], be[4];
    #pragma unroll
    for (int ni = 0; ni < 4; ni++) {
        int c = n0 + wn + ni * 16 + lrow;
        bv[ni] = bia[c];
        float g = bnp[c], vr = bnp[3 * N + c];
        mn[ni] = bnp[2 * N + c]; be[ni] = bnp[N + c];
        sc[ni] = g * rsqrtf(vr + 1e-3f);
    }
    int p0 = n0 + lrow * 8 + (wave & 1) * 4;
    #pragma unroll
    for (int mi = 0; mi < 4; mi++) {
        #pragma unroll
        for (int r = 0; r < 4; r++) {
            h4 pack;
            #pragma unroll
            for (int ni = 0; ni < 4; ni++) {
                float v = acc[mi][ni][r] + bv[ni];
                v = fmaxf(v, 0.f);
                v = sc[ni] * (v - mn[ni]) + be[ni];
                pack[ni] = (_Float16)v;
            }
            int row = m0 + wm + mi * 16 + lq * 4 + r;
            *(h4*)(out + (size_t)row * N + p0) = pack;
        }
    }
}

// ---- pool (f16): max over {self, neighbors}; 16B/lane, 8 atoms/block ---
__global__ __launch_bounds__(256) void pool_f16_kernel(
    const _Float16* __restrict__ x,
    const int* __restrict__ a1, const int* __restrict__ a2,
    const int* __restrict__ a3, const int* __restrict__ a4,
    _Float16* __restrict__ out) {
    int atom = blockIdx.x * 8 + (threadIdx.x >> 5);
    int l = threadIdx.x & 31;
    int d, loc; const int* adj;
    atom_seg(atom, d, loc, a1, a2, a3, a4, adj);
    half8 m = *(const half8*)(x + (size_t)atom * 256 + l * 8);
    float mv[8];
    #pragma unroll
    for (int e = 0; e < 8; e++) mv[e] = (float)m[e];
    for (int j = 0; j < d; j++) {
        int nb = adj[(size_t)loc * d + j];
        half8 v = *(const half8*)(x + (size_t)nb * 256 + l * 8);
        #pragma unroll
        for (int e = 0; e < 8; e++) mv[e] = fmaxf(mv[e], (float)v[e]);
    }
    half8 o;
    #pragma unroll
    for (int e = 0; e < 8; e++) o[e] = (_Float16)mv[e];
    *(half8*)(out + (size_t)atom * 256 + l * 8) = o;
}

// ---- segment reduce (un-permutes) --------------------------------------
__global__ __launch_bounds__(512) void seg_reduce_kernel(
    const _Float16* __restrict__ h, const int* __restrict__ count,
    const int* __restrict__ list, float* __restrict__ fp) {
    int seg = blockIdx.x, c = threadIdx.x;        // c = stored position
    int chan = unperm128(c);                      // true channel
    int n = count[seg]; if (n > MAXSEG) n = MAXSEG;
    float sum = 0.f, mx = -INFINITY;
    for (int a = 0; a < n; a++) {
        int row = list[seg * MAXSEG + a];
        float v = (float)h[(size_t)row * 512 + c];
        sum += v; mx = fmaxf(mx, v);
    }
    fp[(size_t)seg * 1024 + chan] = tanhf(sum);
    fp[(size_t)seg * 1024 + 512 + chan] = tanhf(mx);
}

// ---- head --------------------------------------------------------------
__global__ __launch_bounds__(256) void head_kernel(
    const float* __restrict__ fp, const float* __restrict__ hWt,
    const float* __restrict__ hb, float* __restrict__ logits,
    float* __restrict__ probs) {
    __shared__ float fps[1024];
    __shared__ float red[32];
    int s = blockIdx.x;
    for (int i = threadIdx.x; i < 1024; i += 256) fps[i] = fp[(size_t)s * 1024 + i];
    __syncthreads();
    int t = threadIdx.x;
    int o = t >> 3, kp = t & 7;
    float acc = 0.f;
    if (o < 24) {
        const float* w = hWt + (size_t)o * 1024 + kp * 128;
        const float* f = fps + kp * 128;
        #pragma unroll 8
        for (int i = 0; i < 128; i++) acc = fmaf(f[i], w[i], acc);
    }
    acc += __shfl_down(acc, 4, 64);
    acc += __shfl_down(acc, 2, 64);
    acc += __shfl_down(acc, 1, 64);
    if (o < 24 && kp == 0) red[o] = acc + hb[o];
    __syncthreads();
    if (t < 24) {
        float a = red[t];
        float an = red[t ^ 1];
        logits[(size_t)s * 24 + t] = a;
        probs[(size_t)s * 24 + t] = 1.f / (1.f + expf(an - a));
    }
}

extern "C" void kernel_launch(void* const* d_in, const int* in_sizes, int n_in,
                              void* d_out, int out_size, void* d_ws, size_t ws_size,
                              hipStream_t stream) {
    const float* af         = (const float*)d_in[0];
    const int*   membership = (const int*)d_in[2];
    const int*   a1 = (const int*)d_in[4];
    const int*   a2 = (const int*)d_in[5];
    const int*   a3 = (const int*)d_in[6];
    const int*   a4 = (const int*)d_in[7];
    const float* gc1W = (const float*)d_in[8];
    const float* gc1b = (const float*)d_in[9];
    const float* gc2W = (const float*)d_in[10];
    const float* gc2b = (const float*)d_in[11];
    const float* bn1  = (const float*)d_in[12];
    const float* bn2  = (const float*)d_in[13];
    const float* bn3  = (const float*)d_in[14];
    const float* dW   = (const float*)d_in[15];
    const float* db   = (const float*)d_in[16];
    const float* hW   = (const float*)d_in[17];
    const float* hb   = (const float*)d_in[18];

    float* out    = (float*)d_out;
    float* probs  = out;
    float* logits = out + 24576;
    float* fp     = out + 49152;

    _Float16* Wc1  = (_Float16*)d_ws;                 // 5*256*160 = 204800
    _Float16* Wc2  = Wc1 + 204800;                    // 5*256*512 = 655360
    _Float16* dWt  = Wc2 + 655360;                    // 512*256   = 131072
    float* bias1   = (float*)(dWt + 131072);          // 1280
    float* bias2   = bias1 + 1280;                    // 1280
    float* hWt     = bias2 + 1280;                    // 24576
    int* count     = (int*)(hWt + 24576);             // 1024
    int* list      = count + 1024;                    // 163840
    _Float16* bufBig = (_Float16*)(list + 163840);    // NA*512 f16
    _Float16* bufY   = bufBig + (size_t)NA * 512;     // NA*256
    _Float16* bufP   = bufY + (size_t)NA * 256;       // NA*256
    // lifetime plan inside bufBig:
    //   af16 [0, NA*80), Xn1 [NA*80, NA*160)  — used through gemm1
    //   Xn   [NA*256, NA*512)                 — used through gemm2
    //   h    [0, NA*512)                      — dense output (after above die)
    _Float16* af16 = bufBig;
    _Float16* Xn1  = bufBig + (size_t)NA * 80;
    _Float16* Xn   = bufBig + (size_t)NA * 256;
    _Float16* h    = bufBig;

    prep_kernel<<<9092, 256, 0, stream>>>(af, gc1W, gc1b, gc2W, gc2b, dW, hW,
                                          af16, Wc1, bias1, Wc2, bias2, dWt, hWt, count);
    bucket_kernel<<<256, 256, 0, stream>>>(membership, count, list);
    gather1n_kernel<<<5120, 256, 0, stream>>>(af16, a1, a2, a3, a4, Xn1);
    gemm_kernel<160, 256, 32, 80><<<1024, 256, 0, stream>>>(af16, Xn1, Wc1, bias1, bn1,
                                                            256 * 160, 256, bufY);
    pool_f16_kernel<<<8192, 256, 0, stream>>>(bufY, a1, a2, a3, a4, bufP);
    gather2n_kernel<<<8192, 256, 0, stream>>>(bufP, a1, a2, a3, a4, Xn);
    gemm_kernel<512, 256, 64, 256><<<1024, 256, 0, stream>>>(bufP, Xn, Wc2, bias2, bn2,
                                                             256 * 512, 256, bufY);
    pool_f16_kernel<<<8192, 256, 0, stream>>>(bufY, a1, a2, a3, a4, bufP);
    gemm_kernel<256, 512, 64, 0><<<2048, 256, 0, stream>>>(bufP, nullptr, dWt, db, bn3,
                                                           0, 0, h);
    seg_reduce_kernel<<<1024, 512, 0, stream>>>(h, count, list, fp);
    head_kernel<<<1024, 256, 0, stream>>>(fp, hWt, hb, logits, probs);
}